// Round 9
// baseline (524.520 us; speedup 1.0000x reference)
//
#include <hip/hip_runtime.h>
#include <math.h>

// ---------------------------------------------------------------------------
// Problem constants
//   x: (B=2, C=64, H=128, W=128) fp32, HW = 16384 tokens per batch
//   spatial mamba: d_model=64, d_inner=128, dt_rank=4, d_state=16, L=16384
//   spectral mamba: per-pixel sequence of TOKEN=8 over channel groups of 8,
//                   d_model=8, d_inner=16, dt_rank=1, d_state=16
// ---------------------------------------------------------------------------

#define NB 2
#define NC 64
#define HW_ 16384
#define SCH 512          // spatial scan chunks per batch
#define SLC 32           // tokens per chunk (16384/512)

__device__ __forceinline__ float sigmoidf_(float v) { return 1.f / (1.f + __expf(-v)); }
__device__ __forceinline__ float siluf_(float v)    { return v * sigmoidf_(v); }
__device__ __forceinline__ float softplusf_(float v) {
    return v > 0.f ? v + log1pf(__expf(-v)) : log1pf(__expf(v));
}
__device__ __forceinline__ float dot4_(float4 a, float4 b) {
    return a.x*b.x + a.y*b.y + a.z*b.z + a.w*b.w;
}

// ---------------------------------------------------------------------------
// K0: transpose x [b][c][l] -> xT [b][l][c]  (for wave-uniform token reads)
// grid 512 (2 b x 256 l-tiles of 64), block 256.
// ---------------------------------------------------------------------------
__global__ __launch_bounds__(256) void k0_transpose(
    const float* __restrict__ x, float* __restrict__ xT)
{
    __shared__ __align__(16) float tile[64 * 68];
    const int tid = threadIdx.x;
    const int b  = blockIdx.x >> 8;
    const int l0 = (blockIdx.x & 255) << 6;
    {
        int c = tid >> 2, lq = tid & 3;
        const float4* src = (const float4*)(x + ((size_t)b * NC + c) * HW_ + l0);
        #pragma unroll
        for (int j = 0; j < 4; ++j) {
            float4 v = src[lq + j * 4];
            *(float4*)(tile + c * 68 + (lq + j * 4) * 4) = v;
        }
    }
    __syncthreads();
    {
        int l = tid >> 2, cq = tid & 3;
        float4* dst = (float4*)(xT + ((size_t)b * HW_ + l0 + l) * 64);
        #pragma unroll
        for (int j = 0; j < 4; ++j) {
            int c4 = cq + j * 4;
            float4 v;
            v.x = tile[(c4 * 4 + 0) * 68 + l];
            v.y = tile[(c4 * 4 + 1) * 68 + l];
            v.z = tile[(c4 * 4 + 2) * 68 + l];
            v.w = tile[(c4 * 4 + 3) * 68 + l];
            dst[c4] = v;
        }
    }
}

// ---------------------------------------------------------------------------
// K1 Phase-B helper: k-outer / token-inner matvec, acc register-blocked.
// Weights loaded ONCE (16 float4 per thread); x rows are wave-uniform loads.
// GUARD=true only for the l0==0 tiles (tokens t<3 are the zero pad).
// ---------------------------------------------------------------------------
template<bool GUARD>
__device__ __forceinline__ void k1_matvec35(
    const float* __restrict__ xbase,   // xT row of token t=0 (= l0-3)
    const float* __restrict__ wrow,    // 64-float weight row for this output
    float* __restrict__ acc)           // acc[35], pre-zeroed
{
    #pragma unroll
    for (int q = 0; q < 16; ++q) {
        float4 w = *(const float4*)(wrow + q * 4);
        #pragma unroll
        for (int t = 0; t < 35; ++t) {
            if (GUARD && t < 3) continue;        // statically pruned pad rows
            float4 xv = *(const float4*)(xbase + (size_t)t * 64 + q * 4);
            acc[t] += w.x*xv.x + w.y*xv.y + w.z*xv.z + w.w*xv.w;
        }
    }
}

// ---------------------------------------------------------------------------
// K1 v7: in_proj (k-outer register-blocked) + conv + x-proj(B,C,dt) + fused
// scan pass 1. grid 1024, block 256, LDS 20.5 KB.
// ---------------------------------------------------------------------------
#define K1_XCL_STR 132       // conv-output tile row stride

__global__ __launch_bounds__(256) void k1_spatial_pre(
    const float* __restrict__ xT, const float* __restrict__ in_w,
    const float* __restrict__ conv_w, const float* __restrict__ conv_b,
    const float* __restrict__ xp_w, const float* __restrict__ dt_w,
    const float* __restrict__ dt_b, const float* __restrict__ A_log,
    float* __restrict__ xc_g, float* __restrict__ sz_g,
    float* __restrict__ dtp_g, float* __restrict__ Bm_g, float* __restrict__ Cm_g,
    float* __restrict__ cumA_g, float* __restrict__ hsum_g)
{
    __shared__ __align__(16) float smem[4480];   // pre (35x128); xcl overlay (32x132)
    __shared__ __align__(16) float sB[512];      // B projection tile
    __shared__ __align__(16) float sdt[128];     // dt projection tile
    const int tid = threadIdx.x;
    const int b   = blockIdx.x >> 9;
    const int l0  = (blockIdx.x & 511) << 5;

    // ---- Phase B: in_proj. Waves 0-1: xc-pre rows (all 35 toks incl halo);
    //      waves 2-3: z rows (toks 3..34). One weight pass, acc[35] in regs. ----
    {
        const int halfsel = tid >> 7;
        const int e = tid & 127;
        const float* wrow = in_w + (size_t)(halfsel * 128 + e) * 64;
        const float* xbase = xT + ((size_t)b * HW_ + l0) * 64 - 192;  // row l0-3
        float acc[35];
        #pragma unroll
        for (int t = 0; t < 35; ++t) acc[t] = 0.f;
        if (l0 != 0) k1_matvec35<false>(xbase, wrow, acc);
        else         k1_matvec35<true >(xbase, wrow, acc);
        if (halfsel == 0) {
            #pragma unroll
            for (int t = 0; t < 35; ++t) smem[t * 128 + e] = acc[t];
        } else {
            #pragma unroll
            for (int t = 3; t < 35; ++t)
                sz_g[((size_t)(b * HW_ + l0 + t - 3)) * 128 + e] = siluf_(acc[t]);
        }
    }
    __syncthreads();

    // ---- Phase C: depthwise causal conv (k=4) + bias + silu ----
    {
        const int e = tid & 127;
        float cw0 = conv_w[e*4], cw1 = conv_w[e*4+1], cw2 = conv_w[e*4+2], cw3 = conv_w[e*4+3];
        float cb = conv_b[e];
        float r[16];
        #pragma unroll
        for (int k = 0; k < 16; ++k) {
            int tok = (tid + k * 256) >> 7;
            float v = cb + cw0 * smem[(tok+0)*128 + e] + cw1 * smem[(tok+1)*128 + e]
                         + cw2 * smem[(tok+2)*128 + e] + cw3 * smem[(tok+3)*128 + e];
            v = siluf_(v);
            r[k] = v;
            xc_g[((size_t)(b * HW_ + l0 + tok)) * 128 + e] = v;
        }
        __syncthreads();
        #pragma unroll
        for (int k = 0; k < 16; ++k) {
            int tok = (tid + k * 256) >> 7;
            smem[tok * K1_XCL_STR + e] = r[k];   // overwrite pre region (barriered)
        }
    }
    __syncthreads();

    // ---- Phase D1: B/C projections, 2 f-rows x 2 tokens per thread ----
    {
        const int f0   = (tid & 15) << 1;
        const int tok0 = (tid >> 4) << 1;
        const float4* x0r = (const float4*)(smem + tok0 * K1_XCL_STR);
        const float4* x1r = (const float4*)(smem + (tok0 + 1) * K1_XCL_STR);
        const float4* w0r = (const float4*)(xp_w + (4 + f0) * 128);
        const float4* w1r = (const float4*)(xp_w + (5 + f0) * 128);
        float a00 = 0.f, a01 = 0.f, a10 = 0.f, a11 = 0.f;
        #pragma unroll
        for (int q = 0; q < 32; ++q) {
            float4 w0 = w0r[q], w1 = w1r[q], p0 = x0r[q], p1 = x1r[q];
            a00 += dot4_(w0, p0); a01 += dot4_(w0, p1);
            a10 += dot4_(w1, p0); a11 += dot4_(w1, p1);
        }
        size_t row0 = (size_t)(b * HW_ + l0 + tok0);
        if (f0 < 16) {
            Bm_g[row0 * 16 + f0]           = a00; Bm_g[row0 * 16 + f0 + 1]       = a10;
            Bm_g[(row0 + 1) * 16 + f0]     = a01; Bm_g[(row0 + 1) * 16 + f0 + 1] = a11;
            sB[tok0 * 16 + f0]       = a00; sB[tok0 * 16 + f0 + 1]       = a10;
            sB[(tok0 + 1) * 16 + f0] = a01; sB[(tok0 + 1) * 16 + f0 + 1] = a11;
        } else {
            int g = f0 - 16;
            Cm_g[row0 * 16 + g]           = a00; Cm_g[row0 * 16 + g + 1]       = a10;
            Cm_g[(row0 + 1) * 16 + g]     = a01; Cm_g[(row0 + 1) * 16 + g + 1] = a11;
        }
    }
    // ---- Phase D2: dt projection (rows 0..3), one (token,r) per thread ----
    if (tid < 128) {
        int tok = tid >> 2;
        const float4* xr = (const float4*)(smem + tok * K1_XCL_STR);
        const float4* wr = (const float4*)(xp_w + (tid & 3) * 128);
        float acc = 0.f;
        #pragma unroll
        for (int q = 0; q < 32; ++q) {
            float4 a = xr[q], w4 = wr[q];
            acc += dot4_(a, w4);
        }
        dtp_g[(size_t)(b * HW_ + l0) * 4 + tid] = acc;   // coalesced
        sdt[tid] = acc;
    }
    __syncthreads();

    // ---- Phase E (fused scan pass 1): this tile IS one chunk of 32 ----
    {
        const int e = tid >> 1;
        const int n0 = (tid & 1) * 8;
        float A[8];
        #pragma unroll
        for (int j = 0; j < 8; ++j) A[j] = -__expf(A_log[e * 16 + n0 + j]);
        float4 wdt = *(const float4*)(dt_w + e * 4);
        float dtb = dt_b[e];
        float h[8], cA[8];
        #pragma unroll
        for (int j = 0; j < 8; ++j) { h[j] = 0.f; cA[j] = 1.f; }
        for (int t = 0; t < 32; ++t) {
            float4 dv = *(const float4*)(sdt + t * 4);
            float d = softplusf_(wdt.x*dv.x + wdt.y*dv.y + wdt.z*dv.z + wdt.w*dv.w + dtb);
            float u = smem[t * K1_XCL_STR + e];
            float4 b0 = *(const float4*)(sB + t * 16 + n0);
            float4 b1 = *(const float4*)(sB + t * 16 + n0 + 4);
            float Bv[8]; *(float4*)(Bv) = b0; *(float4*)(Bv + 4) = b1;
            float du = d * u;
            #pragma unroll
            for (int j = 0; j < 8; ++j) {
                float dA = __expf(d * A[j]);
                h[j] = h[j] * dA + du * Bv[j];
                cA[j] *= dA;
            }
        }
        size_t so = (size_t)blockIdx.x * 2048 + tid * 8;
        *(float4*)(cumA_g + so)     = *(float4*)(cA);
        *(float4*)(cumA_g + so + 4) = *(float4*)(cA + 4);
        *(float4*)(hsum_g + so)     = *(float4*)(h);
        *(float4*)(hsum_g + so + 4) = *(float4*)(h + 4);
    }
}

// ---------------------------------------------------------------------------
// K3: cross-chunk exclusive combine (4096 independent streams, 512 steps).
// NOTE: Hin_g aliases cumA_g (loads of a batch precede its stores; each
// stream owns its column exclusively) — no __restrict__ here.
// ---------------------------------------------------------------------------
__global__ __launch_bounds__(256) void k3_combine(
    const float* cumA_g, const float* hsum_g, float* Hin_g)
{
    int gid = blockIdx.x * 256 + threadIdx.x;     // 0..4095
    int b = gid >> 11;
    int en = gid & 2047;
    float st = 0.f;
    size_t o = (size_t)b * SCH * 2048 + en;
    for (int cb = 0; cb < SCH; cb += 16) {
        float a[16], hs[16];
        #pragma unroll
        for (int k = 0; k < 16; ++k) {
            a[k]  = cumA_g[o + (size_t)k * 2048];
            hs[k] = hsum_g[o + (size_t)k * 2048];
        }
        #pragma unroll
        for (int k = 0; k < 16; ++k) {
            Hin_g[o + (size_t)k * 2048] = st;
            st = st * a[k] + hs[k];
        }
        o += (size_t)16 * 2048;
    }
}

// ---------------------------------------------------------------------------
// K4: spatial scan pass 2 + gating + out_proj + NCHW store + GN partials.
// grid 1024, block 256. out_proj: 2 c-rows x 4 tokens per thread.
// ---------------------------------------------------------------------------
__global__ __launch_bounds__(256) void k4_scan2(
    const float* __restrict__ xc_g, const float* __restrict__ sz_g,
    const float* __restrict__ Bm_g, const float* __restrict__ Cm_g,
    const float* __restrict__ dtp_g, const float* __restrict__ dt_w,
    const float* __restrict__ dt_b, const float* __restrict__ A_log,
    const float* __restrict__ Dp, const float* __restrict__ Hin_g,
    const float* __restrict__ out_w,
    float* __restrict__ spa_raw, float* __restrict__ part_spa)
{
    __shared__ __align__(16) float lds[9344];
    float* su  = lds;               // 4096: xc chunk [t][e]
    float* sB  = lds + 4096;        // 512
    float* sC  = lds + 4608;        // 512
    float* sdt = lds + 5120;        // 128
    float* yt  = lds + 5248;        // 4096: y'(t,e)
    float* ot  = lds;               // 2112: out(c,t) — overlays su post-scan
    __shared__ float wred[32];
    const int tid = threadIdx.x;
    const int b = blockIdx.x >> 9;
    const int ch = blockIdx.x & 511;
    const size_t rowbase = (size_t)b * HW_ + ch * SLC;

    const float4* u4 = (const float4*)(xc_g + rowbase * 128);
    #pragma unroll
    for (int j = 0; j < 4; ++j) ((float4*)su)[tid + j * 256] = u4[tid + j * 256];
    if (tid < 128) ((float4*)sB)[tid] = ((const float4*)(Bm_g + rowbase * 16))[tid];
    else           ((float4*)sC)[tid - 128] = ((const float4*)(Cm_g + rowbase * 16))[tid - 128];
    if (tid < 32)  ((float4*)sdt)[tid] = ((const float4*)(dtp_g + rowbase * 4))[tid];

    const int e = tid >> 1;
    const int nh = tid & 1;
    const int n0 = nh * 8;
    float A[8];
    #pragma unroll
    for (int j = 0; j < 8; ++j) A[j] = -__expf(A_log[e * 16 + n0 + j]);
    float4 wdt = *(const float4*)(dt_w + e * 4);
    float dtb = dt_b[e];
    float Dv = Dp[e];
    float h[8];
    size_t so = (size_t)blockIdx.x * 2048 + tid * 8;
    *(float4*)(h)     = *(const float4*)(Hin_g + so);
    *(float4*)(h + 4) = *(const float4*)(Hin_g + so + 4);
    __syncthreads();

    for (int t = 0; t < SLC; ++t) {
        float4 dv = *(const float4*)(sdt + t * 4);
        float d = softplusf_(wdt.x*dv.x + wdt.y*dv.y + wdt.z*dv.z + wdt.w*dv.w + dtb);
        float u = su[t * 128 + e];
        float4 b0 = *(const float4*)(sB + t * 16 + n0);
        float4 b1 = *(const float4*)(sB + t * 16 + n0 + 4);
        float4 c0 = *(const float4*)(sC + t * 16 + n0);
        float4 c1 = *(const float4*)(sC + t * 16 + n0 + 4);
        float Bv[8]; *(float4*)(Bv) = b0; *(float4*)(Bv + 4) = b1;
        float Cv[8]; *(float4*)(Cv) = c0; *(float4*)(Cv + 4) = c1;
        float du = d * u;
        float y = 0.f;
        #pragma unroll
        for (int j = 0; j < 8; ++j) {
            float dA = __expf(d * A[j]);
            h[j] = h[j] * dA + du * Bv[j];
            y += h[j] * Cv[j];
        }
        y += __shfl_xor(y, 1, 64);          // combine both n-halves
        if (nh == 0) yt[t * 128 + e] = y + u * Dv;
    }
    __syncthreads();

    // ---- gate pass: yt *= silu(z), coalesced float4 global reads ----
    {
        const float4* sz4 = (const float4*)(sz_g + rowbase * 128);
        #pragma unroll
        for (int j = 0; j < 4; ++j) {
            int f = tid + j * 256;
            float4 yv = ((float4*)yt)[f];
            float4 sv = sz4[f];
            yv.x *= sv.x; yv.y *= sv.y; yv.z *= sv.z; yv.w *= sv.w;
            ((float4*)yt)[f] = yv;
        }
    }
    __syncthreads();

    // ---- out_proj: 2 c-rows x 4 tokens per thread ----
    {
        const int c0 = (tid & 31) << 1;
        const int t0 = (tid >> 5) << 2;
        const float4* w0r = (const float4*)(out_w + c0 * 128);
        const float4* w1r = (const float4*)(out_w + (c0 + 1) * 128);
        float a0[4] = {0.f, 0.f, 0.f, 0.f}, a1[4] = {0.f, 0.f, 0.f, 0.f};
        #pragma unroll
        for (int q = 0; q < 32; ++q) {
            float4 w0 = w0r[q], w1 = w1r[q];
            #pragma unroll
            for (int j = 0; j < 4; ++j) {
                float4 yv = *(const float4*)(yt + (t0 + j) * 128 + q * 4);
                a0[j] += dot4_(w0, yv);
                a1[j] += dot4_(w1, yv);
            }
        }
        __syncthreads();   // all yt reads done before ot (overlaying su) writes
        #pragma unroll
        for (int j = 0; j < 4; ++j) {
            ot[c0 * 33 + t0 + j]       = a0[j];
            ot[(c0 + 1) * 33 + t0 + j] = a1[j];
        }
    }
    __syncthreads();

    // ---- NCHW store ----
    for (int i = tid; i < 64 * SLC; i += 256) {
        int c = i >> 5, t = i & 31;
        spa_raw[((size_t)b * NC + c) * HW_ + ch * SLC + t] = ot[c * 33 + t];
    }
    // ---- GroupNorm partial sums (4 groups of 16 channels) ----
    float s[4], s2[4];
    #pragma unroll
    for (int g = 0; g < 4; ++g) {
        float a = 0.f, a2 = 0.f;
        for (int i = tid; i < 512; i += 256) {
            int c = 16 * g + (i >> 5), t = i & 31;
            float v = ot[c * 33 + t];
            a += v; a2 += v * v;
        }
        s[g] = a; s2[g] = a2;
    }
    #pragma unroll
    for (int g = 0; g < 4; ++g) {
        #pragma unroll
        for (int o = 1; o < 64; o <<= 1) {
            s[g]  += __shfl_xor(s[g], o, 64);
            s2[g] += __shfl_xor(s2[g], o, 64);
        }
    }
    if ((tid & 63) == 0) {
        int w = tid >> 6;
        #pragma unroll
        for (int g = 0; g < 4; ++g) { wred[w*8 + g*2] = s[g]; wred[w*8 + g*2 + 1] = s2[g]; }
    }
    __syncthreads();
    if (tid < 8)   // transposed layout: [slot][block] for coalesced k5b reads
        part_spa[tid * 1024 + blockIdx.x] = wred[tid] + wred[8+tid] + wred[16+tid] + wred[24+tid];
}

// ---------------------------------------------------------------------------
// K5: spectral mamba fused; float4 LDS broadcasts; x staged from xT
// (one coalesced float4 per thread). grid 2048, block 256. LDS 31.9 KB.
// ---------------------------------------------------------------------------
#define K5_STR 144

__global__ __launch_bounds__(256, 2) void k5_spectral(
    const float* __restrict__ xT, const float* __restrict__ in_w,
    const float* __restrict__ conv_w, const float* __restrict__ conv_b,
    const float* __restrict__ xp_w, const float* __restrict__ dt_w,
    const float* __restrict__ dt_b, const float* __restrict__ A_log,
    const float* __restrict__ Dp, const float* __restrict__ out_w,
    float* __restrict__ spe_raw, float* __restrict__ part_spe)
{
    __shared__ __align__(16) float lds[7936];
    float* xcs  = lds;            // [s][t*16+e] stride 144 (2304); ys overlays
    float* sBn  = lds + 2304;     // B rows tile (2304); xin overlays first 1088
    float* sCn  = lds + 4608;     // C rows tile (2304); outs overlays first 1088
    float* souw = lds + 6912;     // out_w staged (1024)
    float* xin  = sBn;            // [j][c] stride 68 (16*68=1088)
    float* ys   = xcs;            // y' tile, same layout as xcs
    float* outs = sCn;            // [c][s] stride 17 (64*17=1088)
    __shared__ float wred[32];
    const int tid = threadIdx.x;
    const int b = blockIdx.x >> 10;
    const int hw0 = (blockIdx.x & 1023) << 4;
    const int s = tid >> 4;       // sequence in block (0..15)
    const int l = tid & 15;       // inner-channel e / state-row n (0..15)

    // ---- Phase 0: stage x tile (coalesced from xT) and out_w ----
    {
        const float4* xt4 = (const float4*)(xT + ((size_t)b * HW_ + hw0) * 64);
        int j = tid >> 4, c4 = (tid & 15) << 2;
        *(float4*)(xin + j * 68 + c4) = xt4[tid];
        ((float4*)souw)[tid] = ((const float4*)out_w)[tid];
    }
    // per-lane weights (global, L2-cached)
    float wi0[8], wi1[8];
    #pragma unroll
    for (int c = 0; c < 8; ++c) { wi0[c] = in_w[l*8 + c]; wi1[c] = in_w[(l+16)*8 + c]; }
    float cw0 = conv_w[l*4], cw1 = conv_w[l*4+1], cw2 = conv_w[l*4+2], cw3 = conv_w[l*4+3];
    float cb = conv_b[l];
    float dtw = dt_w[l], dtb = dt_b[l];
    float wdt[16], wB[16], wC[16];
    #pragma unroll
    for (int e = 0; e < 16; ++e) {
        wdt[e] = xp_w[e];
        wB[e]  = xp_w[(1 + l) * 16 + e];
        wC[e]  = xp_w[(17 + l) * 16 + e];
    }
    __syncthreads();

    // ---- Phase 1: in_proj (float4 broadcast reads) + conv, in registers ----
    float pre[8], sz[8];
    #pragma unroll
    for (int t = 0; t < 8; ++t) {
        float4 x0 = *(const float4*)(xin + s * 68 + t * 8);
        float4 x1 = *(const float4*)(xin + s * 68 + t * 8 + 4);
        float a0 = wi0[0]*x0.x + wi0[1]*x0.y + wi0[2]*x0.z + wi0[3]*x0.w
                 + wi0[4]*x1.x + wi0[5]*x1.y + wi0[6]*x1.z + wi0[7]*x1.w;
        float a1 = wi1[0]*x0.x + wi1[1]*x0.y + wi1[2]*x0.z + wi1[3]*x0.w
                 + wi1[4]*x1.x + wi1[5]*x1.y + wi1[6]*x1.z + wi1[7]*x1.w;
        pre[t] = a0; sz[t] = siluf_(a1);
    }
    float xcv[8];
    #pragma unroll
    for (int t = 0; t < 8; ++t) {
        float v = cb + cw3 * pre[t];
        if (t >= 1) v += cw2 * pre[t-1];
        if (t >= 2) v += cw1 * pre[t-2];
        if (t >= 3) v += cw0 * pre[t-3];
        xcv[t] = siluf_(v);
    }
    #pragma unroll
    for (int t = 0; t < 8; ++t) xcs[s * K5_STR + t * 16 + l] = xcv[t];
    __syncthreads();

    // ---- Phase 2: x-projections; lane l computes rows B_l, C_l, dt ----
    float del[8];
    #pragma unroll
    for (int t = 0; t < 8; ++t) {
        const float4* xr = (const float4*)(xcs + s * K5_STR + t * 16);
        float4 v0 = xr[0], v1 = xr[1], v2 = xr[2], v3 = xr[3];
        float bn = wB[0]*v0.x + wB[1]*v0.y + wB[2]*v0.z + wB[3]*v0.w
                 + wB[4]*v1.x + wB[5]*v1.y + wB[6]*v1.z + wB[7]*v1.w
                 + wB[8]*v2.x + wB[9]*v2.y + wB[10]*v2.z + wB[11]*v2.w
                 + wB[12]*v3.x + wB[13]*v3.y + wB[14]*v3.z + wB[15]*v3.w;
        float cn = wC[0]*v0.x + wC[1]*v0.y + wC[2]*v0.z + wC[3]*v0.w
                 + wC[4]*v1.x + wC[5]*v1.y + wC[6]*v1.z + wC[7]*v1.w
                 + wC[8]*v2.x + wC[9]*v2.y + wC[10]*v2.z + wC[11]*v2.w
                 + wC[12]*v3.x + wC[13]*v3.y + wC[14]*v3.z + wC[15]*v3.w;
        float d0 = wdt[0]*v0.x + wdt[1]*v0.y + wdt[2]*v0.z + wdt[3]*v0.w
                 + wdt[4]*v1.x + wdt[5]*v1.y + wdt[6]*v1.z + wdt[7]*v1.w
                 + wdt[8]*v2.x + wdt[9]*v2.y + wdt[10]*v2.z + wdt[11]*v2.w
                 + wdt[12]*v3.x + wdt[13]*v3.y + wdt[14]*v3.z + wdt[15]*v3.w;
        sBn[s * K5_STR + t * 16 + l] = bn;
        sCn[s * K5_STR + t * 16 + l] = cn;
        del[t] = softplusf_(d0 * dtw + dtb);
    }
    __syncthreads();

    // ---- Phase 3: selective scan, 16 states/lane, B/C via b128 broadcast ----
    float A[16];
    #pragma unroll
    for (int n = 0; n < 16; ++n) A[n] = -__expf(A_log[l * 16 + n]);
    float Dv = Dp[l];
    float h[16];
    #pragma unroll
    for (int n = 0; n < 16; ++n) h[n] = 0.f;
    #pragma unroll
    for (int t = 0; t < 8; ++t) {
        float d = del[t], u = xcv[t];
        float du = d * u;
        float y = 0.f;
        const float4* Bp = (const float4*)(sBn + s * K5_STR + t * 16);
        const float4* Cp = (const float4*)(sCn + s * K5_STR + t * 16);
        #pragma unroll
        for (int q = 0; q < 4; ++q) {
            float4 Bq = Bp[q], Cq = Cp[q];
            float dA;
            dA = __expf(d*A[4*q+0]); h[4*q+0] = h[4*q+0]*dA + du*Bq.x; y += h[4*q+0]*Cq.x;
            dA = __expf(d*A[4*q+1]); h[4*q+1] = h[4*q+1]*dA + du*Bq.y; y += h[4*q+1]*Cq.y;
            dA = __expf(d*A[4*q+2]); h[4*q+2] = h[4*q+2]*dA + du*Bq.z; y += h[4*q+2]*Cq.z;
            dA = __expf(d*A[4*q+3]); h[4*q+3] = h[4*q+3]*dA + du*Bq.w; y += h[4*q+3]*Cq.w;
        }
        ys[s * K5_STR + t * 16 + l] = (y + u * Dv) * sz[t];
    }
    __syncthreads();

    // ---- Phase 4: out_proj (weights + y via b128), 4 outputs per lane ----
    {
        int t = l >> 1;
        int db = (l & 1) * 4;
        const float4* yr = (const float4*)(ys + s * K5_STR + t * 16);
        float4 y0 = yr[0], y1 = yr[1], y2 = yr[2], y3 = yr[3];
        #pragma unroll
        for (int jj = 0; jj < 4; ++jj) {
            int dd = db + jj;
            const float4* wr = (const float4*)(souw + dd * 16);
            float4 w0 = wr[0], w1 = wr[1], w2 = wr[2], w3 = wr[3];
            float acc = dot4_(w0, y0) + dot4_(w1, y1) + dot4_(w2, y2) + dot4_(w3, y3);
            outs[(t * 8 + dd) * 17 + s] = acc;   // channel c = t*8+dd
        }
    }
    __syncthreads();

    // ---- Phase 5: coalesced NCHW store + GN partials (k == group g) ----
    float sg[4], sg2[4];
    #pragma unroll
    for (int k = 0; k < 4; ++k) {
        int i = tid + k * 256;
        int c = i >> 4, j = i & 15;
        float v = outs[c * 17 + j];
        spe_raw[((size_t)b * NC + c) * HW_ + hw0 + j] = v;
        sg[k] = v; sg2[k] = v * v;
    }
    #pragma unroll
    for (int k = 0; k < 4; ++k) {
        #pragma unroll
        for (int o = 1; o < 64; o <<= 1) {
            sg[k]  += __shfl_xor(sg[k], o, 64);
            sg2[k] += __shfl_xor(sg2[k], o, 64);
        }
    }
    if ((tid & 63) == 0) {
        int w = tid >> 6;
        #pragma unroll
        for (int k = 0; k < 4; ++k) { wred[w*8 + k*2] = sg[k]; wred[w*8 + k*2 + 1] = sg2[k]; }
    }
    __syncthreads();
    if (tid < 8)   // transposed layout: [slot][block]
        part_spe[tid * 2048 + blockIdx.x] = wred[tid] + wred[8+tid] + wred[16+tid] + wred[24+tid];
}

// ---------------------------------------------------------------------------
// K5b: reduce GN partials -> (mean, rstd); coalesced float4 reads.
// partials layout: [slot=g*2+st][block], spa 8x1024, spe 8x2048.
// ---------------------------------------------------------------------------
__global__ __launch_bounds__(256) void k5b_stats(
    const float* __restrict__ part_spa, const float* __restrict__ part_spe,
    float* __restrict__ stats)
{
    __shared__ float fina[16], fine_[16];
    const int tid = threadIdx.x;
    const int combo = tid >> 4;      // bb*8 + g*2 + st
    const int ln = tid & 15;
    const int slot = combo & 7, bb = combo >> 3;
    {
        const float4* p = (const float4*)(part_spa + slot * 1024 + bb * 512);
        float a = 0.f;
        #pragma unroll
        for (int k = 0; k < 8; ++k) {
            float4 v = p[ln * 8 + k];
            a += v.x + v.y + v.z + v.w;
        }
        #pragma unroll
        for (int o = 1; o < 16; o <<= 1) a += __shfl_xor(a, o, 64);
        if (ln == 0) fina[combo] = a;
    }
    {
        const float4* p = (const float4*)(part_spe + slot * 2048 + bb * 1024);
        float a = 0.f;
        #pragma unroll
        for (int k = 0; k < 16; ++k) {
            float4 v = p[ln * 16 + k];
            a += v.x + v.y + v.z + v.w;
        }
        #pragma unroll
        for (int o = 1; o < 16; o <<= 1) a += __shfl_xor(a, o, 64);
        if (ln == 0) fine_[combo] = a;
    }
    __syncthreads();
    if (tid < 16) {
        int branch = tid >> 3, bb2 = (tid >> 2) & 1, g = tid & 3;
        const float* fin = branch ? fine_ : fina;
        float S  = fin[bb2 * 8 + g * 2];
        float S2 = fin[bb2 * 8 + g * 2 + 1];
        const float N = 262144.f;     // 16 channels * 16384 positions
        float mu = S / N;
        float var = S2 / N - mu * mu;
        stats[tid * 2] = mu;
        stats[tid * 2 + 1] = rsqrtf(var + 1e-5f);
    }
}

// ---------------------------------------------------------------------------
// K6: GN-normalize + silu + residual for both branches, softmax fuse, store
// ---------------------------------------------------------------------------
__global__ __launch_bounds__(256) void k6_fuse(
    const float* __restrict__ x, const float* __restrict__ spa_raw,
    const float* __restrict__ spe_raw, const float* __restrict__ stats,
    const float* __restrict__ gwa, const float* __restrict__ gba,
    const float* __restrict__ gwe, const float* __restrict__ gbe,
    const float* __restrict__ fw, float* __restrict__ out)
{
    size_t i4 = (size_t)blockIdx.x * 256 + threadIdx.x;
    size_t base = i4 * 4;
    int b = (int)(base >> 20);
    int rem = (int)(base & 1048575);
    int c = rem >> 14;
    int g = c >> 4;
    int sidx = (b * 4 + g) * 2;
    float ma = stats[sidx],      ra = stats[sidx + 1];
    float me = stats[16 + sidx], re = stats[16 + sidx + 1];
    float wa = gwa[c], ba = gba[c], we = gwe[c], be = gbe[c];
    float f0 = fw[0], f1 = fw[1];
    float mx = fmaxf(f0, f1);
    float e0 = __expf(f0 - mx), e1 = __expf(f1 - mx);
    float inv = 1.f / (e0 + e1);
    float w0 = e0 * inv, w1 = e1 * inv;
    float4 xv = *(const float4*)(x + base);
    float4 av = *(const float4*)(spa_raw + base);
    float4 ev = *(const float4*)(spe_raw + base);
    float xr[4] = {xv.x, xv.y, xv.z, xv.w};
    float ar[4] = {av.x, av.y, av.z, av.w};
    float er[4] = {ev.x, ev.y, ev.z, ev.w};
    float orr[4];
    #pragma unroll
    for (int k = 0; k < 4; ++k) {
        float spa = siluf_((ar[k] - ma) * ra * wa + ba) + xr[k];
        float spe = siluf_((er[k] - me) * re * we + be) + xr[k];
        orr[k] = spa * w0 + spe * w1 + xr[k];
    }
    float4 ov = {orr[0], orr[1], orr[2], orr[3]};
    *(float4*)(out + base) = ov;
}

// ---------------------------------------------------------------------------
extern "C" void kernel_launch(void* const* d_in, const int* in_sizes, int n_in,
                              void* d_out, int out_size, void* d_ws, size_t ws_size,
                              hipStream_t stream)
{
    const float* x      = (const float*)d_in[0];
    const float* a_inw  = (const float*)d_in[1];
    const float* a_cw   = (const float*)d_in[2];
    const float* a_cb   = (const float*)d_in[3];
    const float* a_xp   = (const float*)d_in[4];
    const float* a_dtw  = (const float*)d_in[5];
    const float* a_dtb  = (const float*)d_in[6];
    const float* a_Alog = (const float*)d_in[7];
    const float* a_D    = (const float*)d_in[8];
    const float* a_ow   = (const float*)d_in[9];
    const float* e_inw  = (const float*)d_in[10];
    const float* e_cw   = (const float*)d_in[11];
    const float* e_cb   = (const float*)d_in[12];
    const float* e_xp   = (const float*)d_in[13];
    const float* e_dtw  = (const float*)d_in[14];
    const float* e_dtb  = (const float*)d_in[15];
    const float* e_Alog = (const float*)d_in[16];
    const float* e_D    = (const float*)d_in[17];
    const float* e_ow   = (const float*)d_in[18];
    const float* gwa    = (const float*)d_in[19];
    const float* gba    = (const float*)d_in[20];
    const float* gwe    = (const float*)d_in[21];
    const float* gbe    = (const float*)d_in[22];
    const float* fw     = (const float*)d_in[23];

    float* ws    = (float*)d_ws;
    float* xc    = ws;                    // 4194304
    float* sz    = xc    + 4194304;       // 4194304
    float* Bm    = sz    + 4194304;       // 524288
    float* Cm    = Bm    + 524288;        // 524288
    float* dtp   = Cm    + 524288;        // 131072
    float* cumA  = dtp   + 131072;        // 2097152 (also serves as Hin)
    float* hsum  = cumA  + 2097152;       // 2097152
    float* xT    = hsum  + 2097152;       // 2097152
    float* spa_r = xT    + 2097152;       // 2097152
    float* spe_r = spa_r + 2097152;       // 2097152
    float* pspa  = spe_r + 2097152;       // 8*1024
    float* pspe  = pspa  + 8192;          // 8*2048
    float* stats = pspe  + 16384;         // 32

    k0_transpose<<<512, 256, 0, stream>>>(x, xT);
    k1_spatial_pre<<<1024, 256, 0, stream>>>(xT, a_inw, a_cw, a_cb, a_xp, a_dtw,
                                             a_dtb, a_Alog,
                                             xc, sz, dtp, Bm, Cm, cumA, hsum);
    k3_combine<<<16, 256, 0, stream>>>(cumA, hsum, cumA);   // Hin aliases cumA
    k5_spectral<<<2048, 256, 0, stream>>>(xT, e_inw, e_cw, e_cb, e_xp, e_dtw, e_dtb,
                                          e_Alog, e_D, e_ow, spe_r, pspe);
    k4_scan2<<<1024, 256, 0, stream>>>(xc, sz, Bm, Cm, dtp, a_dtw, a_dtb, a_Alog,
                                       a_D, cumA, a_ow, spa_r, pspa);
    k5b_stats<<<1, 256, 0, stream>>>(pspa, pspe, stats);
    k6_fuse<<<2048, 256, 0, stream>>>(x, spa_r, spe_r, stats, gwa, gba, gwe, gbe, fw,
                                      (float*)d_out);
}

// Round 11
// 386.725 us; speedup vs baseline: 1.3563x; 1.3563x over previous
//
#include <hip/hip_runtime.h>
#include <math.h>

// ---------------------------------------------------------------------------
// Problem constants
//   x: (B=2, C=64, H=128, W=128) fp32, HW = 16384 tokens per batch
//   spatial mamba: d_model=64, d_inner=128, dt_rank=4, d_state=16, L=16384
//   spectral mamba: per-pixel sequence of TOKEN=8 over channel groups of 8,
//                   d_model=8, d_inner=16, dt_rank=1, d_state=16
// ---------------------------------------------------------------------------

#define NB 2
#define NC 64
#define HW_ 16384
#define SCH 512          // spatial scan chunks per batch
#define SLC 32           // tokens per chunk (16384/512)

__device__ __forceinline__ float sigmoidf_(float v) { return 1.f / (1.f + __expf(-v)); }
__device__ __forceinline__ float siluf_(float v)    { return v * sigmoidf_(v); }
__device__ __forceinline__ float softplusf_(float v) {
    return v > 0.f ? v + log1pf(__expf(-v)) : log1pf(__expf(v));
}
__device__ __forceinline__ float dot4_(float4 a, float4 b) {
    return a.x*b.x + a.y*b.y + a.z*b.z + a.w*b.w;
}

// ---------------------------------------------------------------------------
// K0: transpose x [b][c][l] -> xT [b][l][c]  (for wave-uniform token reads)
// grid 512 (2 b x 256 l-tiles of 64), block 256.
// ---------------------------------------------------------------------------
__global__ __launch_bounds__(256) void k0_transpose(
    const float* __restrict__ x, float* __restrict__ xT)
{
    __shared__ __align__(16) float tile[64 * 68];
    const int tid = threadIdx.x;
    const int b  = blockIdx.x >> 8;
    const int l0 = (blockIdx.x & 255) << 6;
    {
        int c = tid >> 2, lq = tid & 3;
        const float4* src = (const float4*)(x + ((size_t)b * NC + c) * HW_ + l0);
        #pragma unroll
        for (int j = 0; j < 4; ++j) {
            float4 v = src[lq + j * 4];
            *(float4*)(tile + c * 68 + (lq + j * 4) * 4) = v;
        }
    }
    __syncthreads();
    {
        int l = tid >> 2, cq = tid & 3;
        float4* dst = (float4*)(xT + ((size_t)b * HW_ + l0 + l) * 64);
        #pragma unroll
        for (int j = 0; j < 4; ++j) {
            int c4 = cq + j * 4;
            float4 v;
            v.x = tile[(c4 * 4 + 0) * 68 + l];
            v.y = tile[(c4 * 4 + 1) * 68 + l];
            v.z = tile[(c4 * 4 + 2) * 68 + l];
            v.w = tile[(c4 * 4 + 3) * 68 + l];
            dst[c4] = v;
        }
    }
}

// ---------------------------------------------------------------------------
// K1 v8: in_proj token-blocked TP=5 (7 passes) — bounded register footprint
// (R9's acc[35] full-unroll ballooned to 168 VGPR / 11% occ; R8's per-token
// weight reloads were 1120 divergent loads). + conv + x-proj + scan pass 1.
// grid 1024, block 256, LDS 20.5 KB.
// ---------------------------------------------------------------------------
#define K1_XCL_STR 132       // conv-output tile row stride

__global__ __launch_bounds__(256) void k1_spatial_pre(
    const float* __restrict__ xT, const float* __restrict__ in_w,
    const float* __restrict__ conv_w, const float* __restrict__ conv_b,
    const float* __restrict__ xp_w, const float* __restrict__ dt_w,
    const float* __restrict__ dt_b, const float* __restrict__ A_log,
    float* __restrict__ xc_g, float* __restrict__ sz_g,
    float* __restrict__ dtp_g, float* __restrict__ Bm_g, float* __restrict__ Cm_g,
    float* __restrict__ cumA_g, float* __restrict__ hsum_g)
{
    __shared__ __align__(16) float smem[4480];   // pre (35x128); xcl overlay (32x132)
    __shared__ __align__(16) float sB[512];      // B projection tile
    __shared__ __align__(16) float sdt[128];     // dt projection tile
    const int tid = threadIdx.x;
    const int b   = blockIdx.x >> 9;
    const int l0  = (blockIdx.x & 511) << 5;

    // ---- Phase B: in_proj. Waves 0-1 (halfsel 0): xc-pre rows (35 incl halo)
    //      -> smem. Waves 2-3 (halfsel 1): z rows -> silu -> sz_g.
    //      7 passes x 5 tokens; weight row re-read per q (compiler may hoist). ----
    {
        const int halfsel = tid >> 7;
        const int e = tid & 127;
        const float4* wrow = (const float4*)(in_w + (size_t)(halfsel * 128 + e) * 64);
        const float* xbase = xT + ((size_t)b * HW_ + l0) * 64 - 192;  // row of token l0-3
        #pragma unroll 1
        for (int pass = 0; pass < 7; ++pass) {
            const int tb = pass * 5;
            float acc[5];
            #pragma unroll
            for (int t = 0; t < 5; ++t) acc[t] = 0.f;
            #pragma unroll
            for (int q = 0; q < 16; ++q) {
                float4 w = wrow[q];
                #pragma unroll
                for (int t = 0; t < 5; ++t) {
                    float4 xv = *(const float4*)(xbase + (size_t)(tb + t) * 64 + q * 4);
                    acc[t] += dot4_(w, xv);
                }
            }
            // l0==0 halo rows (t<3) read in-bounds garbage; zero them (pad = 0).
            if (l0 == 0 && pass == 0) { acc[0] = 0.f; acc[1] = 0.f; acc[2] = 0.f; }
            if (halfsel == 0) {
                #pragma unroll
                for (int t = 0; t < 5; ++t) smem[(tb + t) * 128 + e] = acc[t];
            } else {
                #pragma unroll
                for (int t = 0; t < 5; ++t) {
                    const int tg = tb + t;
                    if (tg >= 3)
                        sz_g[((size_t)(b * HW_ + l0 + tg - 3)) * 128 + e] = siluf_(acc[t]);
                }
            }
        }
    }
    __syncthreads();

    // ---- Phase C: depthwise causal conv (k=4) + bias + silu ----
    {
        const int e = tid & 127;
        float cw0 = conv_w[e*4], cw1 = conv_w[e*4+1], cw2 = conv_w[e*4+2], cw3 = conv_w[e*4+3];
        float cb = conv_b[e];
        float r[16];
        #pragma unroll
        for (int k = 0; k < 16; ++k) {
            int tok = (tid + k * 256) >> 7;
            float v = cb + cw0 * smem[(tok+0)*128 + e] + cw1 * smem[(tok+1)*128 + e]
                         + cw2 * smem[(tok+2)*128 + e] + cw3 * smem[(tok+3)*128 + e];
            v = siluf_(v);
            r[k] = v;
            xc_g[((size_t)(b * HW_ + l0 + tok)) * 128 + e] = v;
        }
        __syncthreads();
        #pragma unroll
        for (int k = 0; k < 16; ++k) {
            int tok = (tid + k * 256) >> 7;
            smem[tok * K1_XCL_STR + e] = r[k];   // overwrite pre region (barriered)
        }
    }
    __syncthreads();

    // ---- Phase D1: B/C projections, 2 f-rows x 2 tokens per thread ----
    {
        const int f0   = (tid & 15) << 1;
        const int tok0 = (tid >> 4) << 1;
        const float4* x0r = (const float4*)(smem + tok0 * K1_XCL_STR);
        const float4* x1r = (const float4*)(smem + (tok0 + 1) * K1_XCL_STR);
        const float4* w0r = (const float4*)(xp_w + (4 + f0) * 128);
        const float4* w1r = (const float4*)(xp_w + (5 + f0) * 128);
        float a00 = 0.f, a01 = 0.f, a10 = 0.f, a11 = 0.f;
        #pragma unroll
        for (int q = 0; q < 32; ++q) {
            float4 w0 = w0r[q], w1 = w1r[q], p0 = x0r[q], p1 = x1r[q];
            a00 += dot4_(w0, p0); a01 += dot4_(w0, p1);
            a10 += dot4_(w1, p0); a11 += dot4_(w1, p1);
        }
        size_t row0 = (size_t)(b * HW_ + l0 + tok0);
        if (f0 < 16) {
            Bm_g[row0 * 16 + f0]           = a00; Bm_g[row0 * 16 + f0 + 1]       = a10;
            Bm_g[(row0 + 1) * 16 + f0]     = a01; Bm_g[(row0 + 1) * 16 + f0 + 1] = a11;
            sB[tok0 * 16 + f0]       = a00; sB[tok0 * 16 + f0 + 1]       = a10;
            sB[(tok0 + 1) * 16 + f0] = a01; sB[(tok0 + 1) * 16 + f0 + 1] = a11;
        } else {
            int g = f0 - 16;
            Cm_g[row0 * 16 + g]           = a00; Cm_g[row0 * 16 + g + 1]       = a10;
            Cm_g[(row0 + 1) * 16 + g]     = a01; Cm_g[(row0 + 1) * 16 + g + 1] = a11;
        }
    }
    // ---- Phase D2: dt projection (rows 0..3), one (token,r) per thread ----
    if (tid < 128) {
        int tok = tid >> 2;
        const float4* xr = (const float4*)(smem + tok * K1_XCL_STR);
        const float4* wr = (const float4*)(xp_w + (tid & 3) * 128);
        float acc = 0.f;
        #pragma unroll
        for (int q = 0; q < 32; ++q) {
            float4 a = xr[q], w4 = wr[q];
            acc += dot4_(a, w4);
        }
        dtp_g[(size_t)(b * HW_ + l0) * 4 + tid] = acc;   // coalesced
        sdt[tid] = acc;
    }
    __syncthreads();

    // ---- Phase E (fused scan pass 1): this tile IS one chunk of 32 ----
    {
        const int e = tid >> 1;
        const int n0 = (tid & 1) * 8;
        float A[8];
        #pragma unroll
        for (int j = 0; j < 8; ++j) A[j] = -__expf(A_log[e * 16 + n0 + j]);
        float4 wdt = *(const float4*)(dt_w + e * 4);
        float dtb = dt_b[e];
        float h[8], cA[8];
        #pragma unroll
        for (int j = 0; j < 8; ++j) { h[j] = 0.f; cA[j] = 1.f; }
        for (int t = 0; t < 32; ++t) {
            float4 dv = *(const float4*)(sdt + t * 4);
            float d = softplusf_(wdt.x*dv.x + wdt.y*dv.y + wdt.z*dv.z + wdt.w*dv.w + dtb);
            float u = smem[t * K1_XCL_STR + e];
            float4 b0 = *(const float4*)(sB + t * 16 + n0);
            float4 b1 = *(const float4*)(sB + t * 16 + n0 + 4);
            float Bv[8]; *(float4*)(Bv) = b0; *(float4*)(Bv + 4) = b1;
            float du = d * u;
            #pragma unroll
            for (int j = 0; j < 8; ++j) {
                float dA = __expf(d * A[j]);
                h[j] = h[j] * dA + du * Bv[j];
                cA[j] *= dA;
            }
        }
        size_t so = (size_t)blockIdx.x * 2048 + tid * 8;
        *(float4*)(cumA_g + so)     = *(float4*)(cA);
        *(float4*)(cumA_g + so + 4) = *(float4*)(cA + 4);
        *(float4*)(hsum_g + so)     = *(float4*)(h);
        *(float4*)(hsum_g + so + 4) = *(float4*)(h + 4);
    }
}

// ---------------------------------------------------------------------------
// K3: cross-chunk exclusive combine (4096 independent streams, 512 steps).
// NOTE: Hin_g aliases cumA_g (loads of a batch precede its stores; each
// stream owns its column exclusively) — no __restrict__ here.
// ---------------------------------------------------------------------------
__global__ __launch_bounds__(256) void k3_combine(
    const float* cumA_g, const float* hsum_g, float* Hin_g)
{
    int gid = blockIdx.x * 256 + threadIdx.x;     // 0..4095
    int b = gid >> 11;
    int en = gid & 2047;
    float st = 0.f;
    size_t o = (size_t)b * SCH * 2048 + en;
    for (int cb = 0; cb < SCH; cb += 16) {
        float a[16], hs[16];
        #pragma unroll
        for (int k = 0; k < 16; ++k) {
            a[k]  = cumA_g[o + (size_t)k * 2048];
            hs[k] = hsum_g[o + (size_t)k * 2048];
        }
        #pragma unroll
        for (int k = 0; k < 16; ++k) {
            Hin_g[o + (size_t)k * 2048] = st;
            st = st * a[k] + hs[k];
        }
        o += (size_t)16 * 2048;
    }
}

// ---------------------------------------------------------------------------
// K4: spatial scan pass 2 + gating + out_proj + NCHW store + GN partials.
// grid 1024, block 256. out_proj: 2 c-rows x 4 tokens per thread.
// ---------------------------------------------------------------------------
__global__ __launch_bounds__(256) void k4_scan2(
    const float* __restrict__ xc_g, const float* __restrict__ sz_g,
    const float* __restrict__ Bm_g, const float* __restrict__ Cm_g,
    const float* __restrict__ dtp_g, const float* __restrict__ dt_w,
    const float* __restrict__ dt_b, const float* __restrict__ A_log,
    const float* __restrict__ Dp, const float* __restrict__ Hin_g,
    const float* __restrict__ out_w,
    float* __restrict__ spa_raw, float* __restrict__ part_spa)
{
    __shared__ __align__(16) float lds[9344];
    float* su  = lds;               // 4096: xc chunk [t][e]
    float* sB  = lds + 4096;        // 512
    float* sC  = lds + 4608;        // 512
    float* sdt = lds + 5120;        // 128
    float* yt  = lds + 5248;        // 4096: y'(t,e)
    float* ot  = lds;               // 2112: out(c,t) — overlays su post-scan
    __shared__ float wred[32];
    const int tid = threadIdx.x;
    const int b = blockIdx.x >> 9;
    const int ch = blockIdx.x & 511;
    const size_t rowbase = (size_t)b * HW_ + ch * SLC;

    const float4* u4 = (const float4*)(xc_g + rowbase * 128);
    #pragma unroll
    for (int j = 0; j < 4; ++j) ((float4*)su)[tid + j * 256] = u4[tid + j * 256];
    if (tid < 128) ((float4*)sB)[tid] = ((const float4*)(Bm_g + rowbase * 16))[tid];
    else           ((float4*)sC)[tid - 128] = ((const float4*)(Cm_g + rowbase * 16))[tid - 128];
    if (tid < 32)  ((float4*)sdt)[tid] = ((const float4*)(dtp_g + rowbase * 4))[tid];

    const int e = tid >> 1;
    const int nh = tid & 1;
    const int n0 = nh * 8;
    float A[8];
    #pragma unroll
    for (int j = 0; j < 8; ++j) A[j] = -__expf(A_log[e * 16 + n0 + j]);
    float4 wdt = *(const float4*)(dt_w + e * 4);
    float dtb = dt_b[e];
    float Dv = Dp[e];
    float h[8];
    size_t so = (size_t)blockIdx.x * 2048 + tid * 8;
    *(float4*)(h)     = *(const float4*)(Hin_g + so);
    *(float4*)(h + 4) = *(const float4*)(Hin_g + so + 4);
    __syncthreads();

    for (int t = 0; t < SLC; ++t) {
        float4 dv = *(const float4*)(sdt + t * 4);
        float d = softplusf_(wdt.x*dv.x + wdt.y*dv.y + wdt.z*dv.z + wdt.w*dv.w + dtb);
        float u = su[t * 128 + e];
        float4 b0 = *(const float4*)(sB + t * 16 + n0);
        float4 b1 = *(const float4*)(sB + t * 16 + n0 + 4);
        float4 c0 = *(const float4*)(sC + t * 16 + n0);
        float4 c1 = *(const float4*)(sC + t * 16 + n0 + 4);
        float Bv[8]; *(float4*)(Bv) = b0; *(float4*)(Bv + 4) = b1;
        float Cv[8]; *(float4*)(Cv) = c0; *(float4*)(Cv + 4) = c1;
        float du = d * u;
        float y = 0.f;
        #pragma unroll
        for (int j = 0; j < 8; ++j) {
            float dA = __expf(d * A[j]);
            h[j] = h[j] * dA + du * Bv[j];
            y += h[j] * Cv[j];
        }
        y += __shfl_xor(y, 1, 64);          // combine both n-halves
        if (nh == 0) yt[t * 128 + e] = y + u * Dv;
    }
    __syncthreads();

    // ---- gate pass: yt *= silu(z), coalesced float4 global reads ----
    {
        const float4* sz4 = (const float4*)(sz_g + rowbase * 128);
        #pragma unroll
        for (int j = 0; j < 4; ++j) {
            int f = tid + j * 256;
            float4 yv = ((float4*)yt)[f];
            float4 sv = sz4[f];
            yv.x *= sv.x; yv.y *= sv.y; yv.z *= sv.z; yv.w *= sv.w;
            ((float4*)yt)[f] = yv;
        }
    }
    __syncthreads();

    // ---- out_proj: 2 c-rows x 4 tokens per thread ----
    {
        const int c0 = (tid & 31) << 1;
        const int t0 = (tid >> 5) << 2;
        const float4* w0r = (const float4*)(out_w + c0 * 128);
        const float4* w1r = (const float4*)(out_w + (c0 + 1) * 128);
        float a0[4] = {0.f, 0.f, 0.f, 0.f}, a1[4] = {0.f, 0.f, 0.f, 0.f};
        #pragma unroll
        for (int q = 0; q < 32; ++q) {
            float4 w0 = w0r[q], w1 = w1r[q];
            #pragma unroll
            for (int j = 0; j < 4; ++j) {
                float4 yv = *(const float4*)(yt + (t0 + j) * 128 + q * 4);
                a0[j] += dot4_(w0, yv);
                a1[j] += dot4_(w1, yv);
            }
        }
        __syncthreads();   // all yt reads done before ot (overlaying su) writes
        #pragma unroll
        for (int j = 0; j < 4; ++j) {
            ot[c0 * 33 + t0 + j]       = a0[j];
            ot[(c0 + 1) * 33 + t0 + j] = a1[j];
        }
    }
    __syncthreads();

    // ---- NCHW store ----
    for (int i = tid; i < 64 * SLC; i += 256) {
        int c = i >> 5, t = i & 31;
        spa_raw[((size_t)b * NC + c) * HW_ + ch * SLC + t] = ot[c * 33 + t];
    }
    // ---- GroupNorm partial sums (4 groups of 16 channels) ----
    float s[4], s2[4];
    #pragma unroll
    for (int g = 0; g < 4; ++g) {
        float a = 0.f, a2 = 0.f;
        for (int i = tid; i < 512; i += 256) {
            int c = 16 * g + (i >> 5), t = i & 31;
            float v = ot[c * 33 + t];
            a += v; a2 += v * v;
        }
        s[g] = a; s2[g] = a2;
    }
    #pragma unroll
    for (int g = 0; g < 4; ++g) {
        #pragma unroll
        for (int o = 1; o < 64; o <<= 1) {
            s[g]  += __shfl_xor(s[g], o, 64);
            s2[g] += __shfl_xor(s2[g], o, 64);
        }
    }
    if ((tid & 63) == 0) {
        int w = tid >> 6;
        #pragma unroll
        for (int g = 0; g < 4; ++g) { wred[w*8 + g*2] = s[g]; wred[w*8 + g*2 + 1] = s2[g]; }
    }
    __syncthreads();
    if (tid < 8)   // transposed layout: [slot][block] for coalesced k5b reads
        part_spa[tid * 1024 + blockIdx.x] = wred[tid] + wred[8+tid] + wred[16+tid] + wred[24+tid];
}

// ---------------------------------------------------------------------------
// K5: spectral mamba fused; float4 LDS broadcasts; x staged from xT
// (one coalesced float4 per thread). grid 2048, block 256. LDS 31.9 KB.
// ---------------------------------------------------------------------------
#define K5_STR 144

__global__ __launch_bounds__(256, 2) void k5_spectral(
    const float* __restrict__ xT, const float* __restrict__ in_w,
    const float* __restrict__ conv_w, const float* __restrict__ conv_b,
    const float* __restrict__ xp_w, const float* __restrict__ dt_w,
    const float* __restrict__ dt_b, const float* __restrict__ A_log,
    const float* __restrict__ Dp, const float* __restrict__ out_w,
    float* __restrict__ spe_raw, float* __restrict__ part_spe)
{
    __shared__ __align__(16) float lds[7936];
    float* xcs  = lds;            // [s][t*16+e] stride 144 (2304); ys overlays
    float* sBn  = lds + 2304;     // B rows tile (2304); xin overlays first 1088
    float* sCn  = lds + 4608;     // C rows tile (2304); outs overlays first 1088
    float* souw = lds + 6912;     // out_w staged (1024)
    float* xin  = sBn;            // [j][c] stride 68 (16*68=1088)
    float* ys   = xcs;            // y' tile, same layout as xcs
    float* outs = sCn;            // [c][s] stride 17 (64*17=1088)
    __shared__ float wred[32];
    const int tid = threadIdx.x;
    const int b = blockIdx.x >> 10;
    const int hw0 = (blockIdx.x & 1023) << 4;
    const int s = tid >> 4;       // sequence in block (0..15)
    const int l = tid & 15;       // inner-channel e / state-row n (0..15)

    // ---- Phase 0: stage x tile (coalesced from xT) and out_w ----
    {
        const float4* xt4 = (const float4*)(xT + ((size_t)b * HW_ + hw0) * 64);
        int j = tid >> 4, c4 = (tid & 15) << 2;
        *(float4*)(xin + j * 68 + c4) = xt4[tid];
        ((float4*)souw)[tid] = ((const float4*)out_w)[tid];
    }
    // per-lane weights (global, L2-cached)
    float wi0[8], wi1[8];
    #pragma unroll
    for (int c = 0; c < 8; ++c) { wi0[c] = in_w[l*8 + c]; wi1[c] = in_w[(l+16)*8 + c]; }
    float cw0 = conv_w[l*4], cw1 = conv_w[l*4+1], cw2 = conv_w[l*4+2], cw3 = conv_w[l*4+3];
    float cb = conv_b[l];
    float dtw = dt_w[l], dtb = dt_b[l];
    float wdt[16], wB[16], wC[16];
    #pragma unroll
    for (int e = 0; e < 16; ++e) {
        wdt[e] = xp_w[e];
        wB[e]  = xp_w[(1 + l) * 16 + e];
        wC[e]  = xp_w[(17 + l) * 16 + e];
    }
    __syncthreads();

    // ---- Phase 1: in_proj (float4 broadcast reads) + conv, in registers ----
    float pre[8], sz[8];
    #pragma unroll
    for (int t = 0; t < 8; ++t) {
        float4 x0 = *(const float4*)(xin + s * 68 + t * 8);
        float4 x1 = *(const float4*)(xin + s * 68 + t * 8 + 4);
        float a0 = wi0[0]*x0.x + wi0[1]*x0.y + wi0[2]*x0.z + wi0[3]*x0.w
                 + wi0[4]*x1.x + wi0[5]*x1.y + wi0[6]*x1.z + wi0[7]*x1.w;
        float a1 = wi1[0]*x0.x + wi1[1]*x0.y + wi1[2]*x0.z + wi1[3]*x0.w
                 + wi1[4]*x1.x + wi1[5]*x1.y + wi1[6]*x1.z + wi1[7]*x1.w;
        pre[t] = a0; sz[t] = siluf_(a1);
    }
    float xcv[8];
    #pragma unroll
    for (int t = 0; t < 8; ++t) {
        float v = cb + cw3 * pre[t];
        if (t >= 1) v += cw2 * pre[t-1];
        if (t >= 2) v += cw1 * pre[t-2];
        if (t >= 3) v += cw0 * pre[t-3];
        xcv[t] = siluf_(v);
    }
    #pragma unroll
    for (int t = 0; t < 8; ++t) xcs[s * K5_STR + t * 16 + l] = xcv[t];
    __syncthreads();

    // ---- Phase 2: x-projections; lane l computes rows B_l, C_l, dt ----
    float del[8];
    #pragma unroll
    for (int t = 0; t < 8; ++t) {
        const float4* xr = (const float4*)(xcs + s * K5_STR + t * 16);
        float4 v0 = xr[0], v1 = xr[1], v2 = xr[2], v3 = xr[3];
        float bn = wB[0]*v0.x + wB[1]*v0.y + wB[2]*v0.z + wB[3]*v0.w
                 + wB[4]*v1.x + wB[5]*v1.y + wB[6]*v1.z + wB[7]*v1.w
                 + wB[8]*v2.x + wB[9]*v2.y + wB[10]*v2.z + wB[11]*v2.w
                 + wB[12]*v3.x + wB[13]*v3.y + wB[14]*v3.z + wB[15]*v3.w;
        float cn = wC[0]*v0.x + wC[1]*v0.y + wC[2]*v0.z + wC[3]*v0.w
                 + wC[4]*v1.x + wC[5]*v1.y + wC[6]*v1.z + wC[7]*v1.w
                 + wC[8]*v2.x + wC[9]*v2.y + wC[10]*v2.z + wC[11]*v2.w
                 + wC[12]*v3.x + wC[13]*v3.y + wC[14]*v3.z + wC[15]*v3.w;
        float d0 = wdt[0]*v0.x + wdt[1]*v0.y + wdt[2]*v0.z + wdt[3]*v0.w
                 + wdt[4]*v1.x + wdt[5]*v1.y + wdt[6]*v1.z + wdt[7]*v1.w
                 + wdt[8]*v2.x + wdt[9]*v2.y + wdt[10]*v2.z + wdt[11]*v2.w
                 + wdt[12]*v3.x + wdt[13]*v3.y + wdt[14]*v3.z + wdt[15]*v3.w;
        sBn[s * K5_STR + t * 16 + l] = bn;
        sCn[s * K5_STR + t * 16 + l] = cn;
        del[t] = softplusf_(d0 * dtw + dtb);
    }
    __syncthreads();

    // ---- Phase 3: selective scan, 16 states/lane, B/C via b128 broadcast ----
    float A[16];
    #pragma unroll
    for (int n = 0; n < 16; ++n) A[n] = -__expf(A_log[l * 16 + n]);
    float Dv = Dp[l];
    float h[16];
    #pragma unroll
    for (int n = 0; n < 16; ++n) h[n] = 0.f;
    #pragma unroll
    for (int t = 0; t < 8; ++t) {
        float d = del[t], u = xcv[t];
        float du = d * u;
        float y = 0.f;
        const float4* Bp = (const float4*)(sBn + s * K5_STR + t * 16);
        const float4* Cp = (const float4*)(sCn + s * K5_STR + t * 16);
        #pragma unroll
        for (int q = 0; q < 4; ++q) {
            float4 Bq = Bp[q], Cq = Cp[q];
            float dA;
            dA = __expf(d*A[4*q+0]); h[4*q+0] = h[4*q+0]*dA + du*Bq.x; y += h[4*q+0]*Cq.x;
            dA = __expf(d*A[4*q+1]); h[4*q+1] = h[4*q+1]*dA + du*Bq.y; y += h[4*q+1]*Cq.y;
            dA = __expf(d*A[4*q+2]); h[4*q+2] = h[4*q+2]*dA + du*Bq.z; y += h[4*q+2]*Cq.z;
            dA = __expf(d*A[4*q+3]); h[4*q+3] = h[4*q+3]*dA + du*Bq.w; y += h[4*q+3]*Cq.w;
        }
        ys[s * K5_STR + t * 16 + l] = (y + u * Dv) * sz[t];
    }
    __syncthreads();

    // ---- Phase 4: out_proj (weights + y via b128), 4 outputs per lane ----
    {
        int t = l >> 1;
        int db = (l & 1) * 4;
        const float4* yr = (const float4*)(ys + s * K5_STR + t * 16);
        float4 y0 = yr[0], y1 = yr[1], y2 = yr[2], y3 = yr[3];
        #pragma unroll
        for (int jj = 0; jj < 4; ++jj) {
            int dd = db + jj;
            const float4* wr = (const float4*)(souw + dd * 16);
            float4 w0 = wr[0], w1 = wr[1], w2 = wr[2], w3 = wr[3];
            float acc = dot4_(w0, y0) + dot4_(w1, y1) + dot4_(w2, y2) + dot4_(w3, y3);
            outs[(t * 8 + dd) * 17 + s] = acc;   // channel c = t*8+dd
        }
    }
    __syncthreads();

    // ---- Phase 5: coalesced NCHW store + GN partials (k == group g) ----
    float sg[4], sg2[4];
    #pragma unroll
    for (int k = 0; k < 4; ++k) {
        int i = tid + k * 256;
        int c = i >> 4, j = i & 15;
        float v = outs[c * 17 + j];
        spe_raw[((size_t)b * NC + c) * HW_ + hw0 + j] = v;
        sg[k] = v; sg2[k] = v * v;
    }
    #pragma unroll
    for (int k = 0; k < 4; ++k) {
        #pragma unroll
        for (int o = 1; o < 64; o <<= 1) {
            sg[k]  += __shfl_xor(sg[k], o, 64);
            sg2[k] += __shfl_xor(sg2[k], o, 64);
        }
    }
    if ((tid & 63) == 0) {
        int w = tid >> 6;
        #pragma unroll
        for (int k = 0; k < 4; ++k) { wred[w*8 + k*2] = sg[k]; wred[w*8 + k*2 + 1] = sg2[k]; }
    }
    __syncthreads();
    if (tid < 8)   // transposed layout: [slot][block]
        part_spe[tid * 2048 + blockIdx.x] = wred[tid] + wred[8+tid] + wred[16+tid] + wred[24+tid];
}

// ---------------------------------------------------------------------------
// K5b: reduce GN partials -> (mean, rstd); coalesced float4 reads.
// partials layout: [slot=g*2+st][block], spa 8x1024, spe 8x2048.
// ---------------------------------------------------------------------------
__global__ __launch_bounds__(256) void k5b_stats(
    const float* __restrict__ part_spa, const float* __restrict__ part_spe,
    float* __restrict__ stats)
{
    __shared__ float fina[16], fine_[16];
    const int tid = threadIdx.x;
    const int combo = tid >> 4;      // bb*8 + g*2 + st
    const int ln = tid & 15;
    const int slot = combo & 7, bb = combo >> 3;
    {
        const float4* p = (const float4*)(part_spa + slot * 1024 + bb * 512);
        float a = 0.f;
        #pragma unroll
        for (int k = 0; k < 8; ++k) {
            float4 v = p[ln * 8 + k];
            a += v.x + v.y + v.z + v.w;
        }
        #pragma unroll
        for (int o = 1; o < 16; o <<= 1) a += __shfl_xor(a, o, 64);
        if (ln == 0) fina[combo] = a;
    }
    {
        const float4* p = (const float4*)(part_spe + slot * 2048 + bb * 1024);
        float a = 0.f;
        #pragma unroll
        for (int k = 0; k < 16; ++k) {
            float4 v = p[ln * 16 + k];
            a += v.x + v.y + v.z + v.w;
        }
        #pragma unroll
        for (int o = 1; o < 16; o <<= 1) a += __shfl_xor(a, o, 64);
        if (ln == 0) fine_[combo] = a;
    }
    __syncthreads();
    if (tid < 16) {
        int branch = tid >> 3, bb2 = (tid >> 2) & 1, g = tid & 3;
        const float* fin = branch ? fine_ : fina;
        float S  = fin[bb2 * 8 + g * 2];
        float S2 = fin[bb2 * 8 + g * 2 + 1];
        const float N = 262144.f;     // 16 channels * 16384 positions
        float mu = S / N;
        float var = S2 / N - mu * mu;
        stats[tid * 2] = mu;
        stats[tid * 2 + 1] = rsqrtf(var + 1e-5f);
    }
}

// ---------------------------------------------------------------------------
// K6: GN-normalize + silu + residual for both branches, softmax fuse, store
// ---------------------------------------------------------------------------
__global__ __launch_bounds__(256) void k6_fuse(
    const float* __restrict__ x, const float* __restrict__ spa_raw,
    const float* __restrict__ spe_raw, const float* __restrict__ stats,
    const float* __restrict__ gwa, const float* __restrict__ gba,
    const float* __restrict__ gwe, const float* __restrict__ gbe,
    const float* __restrict__ fw, float* __restrict__ out)
{
    size_t i4 = (size_t)blockIdx.x * 256 + threadIdx.x;
    size_t base = i4 * 4;
    int b = (int)(base >> 20);
    int rem = (int)(base & 1048575);
    int c = rem >> 14;
    int g = c >> 4;
    int sidx = (b * 4 + g) * 2;
    float ma = stats[sidx],      ra = stats[sidx + 1];
    float me = stats[16 + sidx], re = stats[16 + sidx + 1];
    float wa = gwa[c], ba = gba[c], we = gwe[c], be = gbe[c];
    float f0 = fw[0], f1 = fw[1];
    float mx = fmaxf(f0, f1);
    float e0 = __expf(f0 - mx), e1 = __expf(f1 - mx);
    float inv = 1.f / (e0 + e1);
    float w0 = e0 * inv, w1 = e1 * inv;
    float4 xv = *(const float4*)(x + base);
    float4 av = *(const float4*)(spa_raw + base);
    float4 ev = *(const float4*)(spe_raw + base);
    float xr[4] = {xv.x, xv.y, xv.z, xv.w};
    float ar[4] = {av.x, av.y, av.z, av.w};
    float er[4] = {ev.x, ev.y, ev.z, ev.w};
    float orr[4];
    #pragma unroll
    for (int k = 0; k < 4; ++k) {
        float spa = siluf_((ar[k] - ma) * ra * wa + ba) + xr[k];
        float spe = siluf_((er[k] - me) * re * we + be) + xr[k];
        orr[k] = spa * w0 + spe * w1 + xr[k];
    }
    float4 ov = {orr[0], orr[1], orr[2], orr[3]};
    *(float4*)(out + base) = ov;
}

// ---------------------------------------------------------------------------
extern "C" void kernel_launch(void* const* d_in, const int* in_sizes, int n_in,
                              void* d_out, int out_size, void* d_ws, size_t ws_size,
                              hipStream_t stream)
{
    const float* x      = (const float*)d_in[0];
    const float* a_inw  = (const float*)d_in[1];
    const float* a_cw   = (const float*)d_in[2];
    const float* a_cb   = (const float*)d_in[3];
    const float* a_xp   = (const float*)d_in[4];
    const float* a_dtw  = (const float*)d_in[5];
    const float* a_dtb  = (const float*)d_in[6];
    const float* a_Alog = (const float*)d_in[7];
    const float* a_D    = (const float*)d_in[8];
    const float* a_ow   = (const float*)d_in[9];
    const float* e_inw  = (const float*)d_in[10];
    const float* e_cw   = (const float*)d_in[11];
    const float* e_cb   = (const float*)d_in[12];
    const float* e_xp   = (const float*)d_in[13];
    const float* e_dtw  = (const float*)d_in[14];
    const float* e_dtb  = (const float*)d_in[15];
    const float* e_Alog = (const float*)d_in[16];
    const float* e_D    = (const float*)d_in[17];
    const float* e_ow   = (const float*)d_in[18];
    const float* gwa    = (const float*)d_in[19];
    const float* gba    = (const float*)d_in[20];
    const float* gwe    = (const float*)d_in[21];
    const float* gbe    = (const float*)d_in[22];
    const float* fw     = (const float*)d_in[23];

    float* ws    = (float*)d_ws;
    float* xc    = ws;                    // 4194304
    float* sz    = xc    + 4194304;       // 4194304
    float* Bm    = sz    + 4194304;       // 524288
    float* Cm    = Bm    + 524288;        // 524288
    float* dtp   = Cm    + 524288;        // 131072
    float* cumA  = dtp   + 131072;        // 2097152 (also serves as Hin)
    float* hsum  = cumA  + 2097152;       // 2097152
    float* xT    = hsum  + 2097152;       // 2097152
    float* spa_r = xT    + 2097152;       // 2097152
    float* spe_r = spa_r + 2097152;       // 2097152
    float* pspa  = spe_r + 2097152;       // 8*1024
    float* pspe  = pspa  + 8192;          // 8*2048
    float* stats = pspe  + 16384;         // 32

    k0_transpose<<<512, 256, 0, stream>>>(x, xT);
    k1_spatial_pre<<<1024, 256, 0, stream>>>(xT, a_inw, a_cw, a_cb, a_xp, a_dtw,
                                             a_dtb, a_Alog,
                                             xc, sz, dtp, Bm, Cm, cumA, hsum);
    k3_combine<<<16, 256, 0, stream>>>(cumA, hsum, cumA);   // Hin aliases cumA
    k5_spectral<<<2048, 256, 0, stream>>>(xT, e_inw, e_cw, e_cb, e_xp, e_dtw, e_dtb,
                                          e_Alog, e_D, e_ow, spe_r, pspe);
    k4_scan2<<<1024, 256, 0, stream>>>(xc, sz, Bm, Cm, dtp, a_dtw, a_dtb, a_Alog,
                                       a_D, cumA, a_ow, spa_r, pspa);
    k5b_stats<<<1, 256, 0, stream>>>(pspa, pspe, stats);
    k6_fuse<<<2048, 256, 0, stream>>>(x, spa_r, spe_r, stats, gwa, gba, gwe, gbe, fw,
                                      (float*)d_out);
}

// Round 12
// 354.233 us; speedup vs baseline: 1.4807x; 1.0917x over previous
//
#include <hip/hip_runtime.h>
#include <math.h>

// ---------------------------------------------------------------------------
// Problem constants
//   x: (B=2, C=64, H=128, W=128) fp32, HW = 16384 tokens per batch
//   spatial mamba: d_model=64, d_inner=128, dt_rank=4, d_state=16, L=16384
//   spectral mamba: per-pixel sequence of TOKEN=8 over channel groups of 8,
//                   d_model=8, d_inner=16, dt_rank=1, d_state=16
// ---------------------------------------------------------------------------

#define NB 2
#define NC 64
#define HW_ 16384
#define SCH 512          // spatial scan chunks per batch
#define SLC 32           // tokens per chunk (16384/512)

__device__ __forceinline__ float sigmoidf_(float v) { return 1.f / (1.f + __expf(-v)); }
__device__ __forceinline__ float siluf_(float v)    { return v * sigmoidf_(v); }
__device__ __forceinline__ float softplusf_(float v) {
    return v > 0.f ? v + log1pf(__expf(-v)) : log1pf(__expf(v));
}
__device__ __forceinline__ float dot4_(float4 a, float4 b) {
    return a.x*b.x + a.y*b.y + a.z*b.z + a.w*b.w;
}

// ---------------------------------------------------------------------------
// K0: transpose x [b][c][l] -> xT [b][l][c]  (for wave-uniform token reads)
// grid 512 (2 b x 256 l-tiles of 64), block 256.
// ---------------------------------------------------------------------------
__global__ __launch_bounds__(256) void k0_transpose(
    const float* __restrict__ x, float* __restrict__ xT)
{
    __shared__ __align__(16) float tile[64 * 68];
    const int tid = threadIdx.x;
    const int b  = blockIdx.x >> 8;
    const int l0 = (blockIdx.x & 255) << 6;
    {
        int c = tid >> 2, lq = tid & 3;
        const float4* src = (const float4*)(x + ((size_t)b * NC + c) * HW_ + l0);
        #pragma unroll
        for (int j = 0; j < 4; ++j) {
            float4 v = src[lq + j * 4];
            *(float4*)(tile + c * 68 + (lq + j * 4) * 4) = v;
        }
    }
    __syncthreads();
    {
        int l = tid >> 2, cq = tid & 3;
        float4* dst = (float4*)(xT + ((size_t)b * HW_ + l0 + l) * 64);
        #pragma unroll
        for (int j = 0; j < 4; ++j) {
            int c4 = cq + j * 4;
            float4 v;
            v.x = tile[(c4 * 4 + 0) * 68 + l];
            v.y = tile[(c4 * 4 + 1) * 68 + l];
            v.z = tile[(c4 * 4 + 2) * 68 + l];
            v.w = tile[(c4 * 4 + 3) * 68 + l];
            dst[c4] = v;
        }
    }
}

// ---------------------------------------------------------------------------
// K1 v7 (R8 form — best measured, 110 us): in_proj with per-token xs[64]
// register staging (x via wave-uniform xT reads, DS-free) + conv + x-proj +
// fused scan pass 1. grid 1024, block 256, LDS 20.5 KB.
// Phase-B variants measured: R8 xs-staged=110us / R9 acc[35]=276us /
// R11 TP=5=137us -> R8 schedule wins; do not re-tune.
// ---------------------------------------------------------------------------
#define K1_XCL_STR 132       // conv-output tile row stride

__global__ __launch_bounds__(256) void k1_spatial_pre(
    const float* __restrict__ xT, const float* __restrict__ in_w,
    const float* __restrict__ conv_w, const float* __restrict__ conv_b,
    const float* __restrict__ xp_w, const float* __restrict__ dt_w,
    const float* __restrict__ dt_b, const float* __restrict__ A_log,
    float* __restrict__ xc_g, float* __restrict__ sz_g,
    float* __restrict__ dtp_g, float* __restrict__ Bm_g, float* __restrict__ Cm_g,
    float* __restrict__ cumA_g, float* __restrict__ hsum_g)
{
    __shared__ __align__(16) float smem[4480];   // pre (35x128); xcl overlay (32x132)
    __shared__ __align__(16) float sB[512];      // B projection tile
    __shared__ __align__(16) float sdt[128];     // dt projection tile
    const int tid = threadIdx.x;
    const int b   = blockIdx.x >> 9;
    const int l0  = (blockIdx.x & 511) << 5;

    // ---- Phase B: in_proj, xc-pre + silu(z) in ONE pass over x tokens.
    //      x row addresses are wave-uniform (readfirstlane'd token-half). ----
    {
        const int e = tid & 127;
        const int th = __builtin_amdgcn_readfirstlane(threadIdx.x >> 7);
        float wxc[64], wz[64];
        #pragma unroll
        for (int q = 0; q < 16; ++q) {
            float4 a = *(const float4*)(in_w + e * 64 + q * 4);
            wxc[q*4] = a.x; wxc[q*4+1] = a.y; wxc[q*4+2] = a.z; wxc[q*4+3] = a.w;
            float4 zz = *(const float4*)(in_w + (128 + e) * 64 + q * 4);
            wz[q*4] = zz.x; wz[q*4+1] = zz.y; wz[q*4+2] = zz.z; wz[q*4+3] = zz.w;
        }
        const int t0 = th ? 18 : 0, t1 = th ? 35 : 18;
        for (int tok = t0; tok < t1; ++tok) {
            const int l = l0 + tok - 3;
            float xs[64];
            if (l >= 0) {
                const float4* xr = (const float4*)(xT + ((size_t)b * HW_ + l) * 64);
                #pragma unroll
                for (int q = 0; q < 16; ++q) *(float4*)(xs + q * 4) = xr[q];
            } else {
                #pragma unroll
                for (int q = 0; q < 64; ++q) xs[q] = 0.f;
            }
            float pre = 0.f;
            #pragma unroll
            for (int k = 0; k < 64; ++k) pre += wxc[k] * xs[k];
            smem[tok * 128 + e] = pre;
            if (tok >= 3) {
                float z = 0.f;
                #pragma unroll
                for (int k = 0; k < 64; ++k) z += wz[k] * xs[k];
                sz_g[((size_t)(b * HW_ + l0 + tok - 3)) * 128 + e] = siluf_(z);
            }
        }
    }
    __syncthreads();

    // ---- Phase C: depthwise causal conv (k=4) + bias + silu ----
    {
        const int e = tid & 127;
        float cw0 = conv_w[e*4], cw1 = conv_w[e*4+1], cw2 = conv_w[e*4+2], cw3 = conv_w[e*4+3];
        float cb = conv_b[e];
        float r[16];
        #pragma unroll
        for (int k = 0; k < 16; ++k) {
            int tok = (tid + k * 256) >> 7;
            float v = cb + cw0 * smem[(tok+0)*128 + e] + cw1 * smem[(tok+1)*128 + e]
                         + cw2 * smem[(tok+2)*128 + e] + cw3 * smem[(tok+3)*128 + e];
            v = siluf_(v);
            r[k] = v;
            xc_g[((size_t)(b * HW_ + l0 + tok)) * 128 + e] = v;
        }
        __syncthreads();
        #pragma unroll
        for (int k = 0; k < 16; ++k) {
            int tok = (tid + k * 256) >> 7;
            smem[tok * K1_XCL_STR + e] = r[k];   // overwrite pre region (barriered)
        }
    }
    __syncthreads();

    // ---- Phase D1: B/C projections, 2 f-rows x 2 tokens per thread ----
    {
        const int f0   = (tid & 15) << 1;
        const int tok0 = (tid >> 4) << 1;
        const float4* x0r = (const float4*)(smem + tok0 * K1_XCL_STR);
        const float4* x1r = (const float4*)(smem + (tok0 + 1) * K1_XCL_STR);
        const float4* w0r = (const float4*)(xp_w + (4 + f0) * 128);
        const float4* w1r = (const float4*)(xp_w + (5 + f0) * 128);
        float a00 = 0.f, a01 = 0.f, a10 = 0.f, a11 = 0.f;
        #pragma unroll
        for (int q = 0; q < 32; ++q) {
            float4 w0 = w0r[q], w1 = w1r[q], p0 = x0r[q], p1 = x1r[q];
            a00 += dot4_(w0, p0); a01 += dot4_(w0, p1);
            a10 += dot4_(w1, p0); a11 += dot4_(w1, p1);
        }
        size_t row0 = (size_t)(b * HW_ + l0 + tok0);
        if (f0 < 16) {
            Bm_g[row0 * 16 + f0]           = a00; Bm_g[row0 * 16 + f0 + 1]       = a10;
            Bm_g[(row0 + 1) * 16 + f0]     = a01; Bm_g[(row0 + 1) * 16 + f0 + 1] = a11;
            sB[tok0 * 16 + f0]       = a00; sB[tok0 * 16 + f0 + 1]       = a10;
            sB[(tok0 + 1) * 16 + f0] = a01; sB[(tok0 + 1) * 16 + f0 + 1] = a11;
        } else {
            int g = f0 - 16;
            Cm_g[row0 * 16 + g]           = a00; Cm_g[row0 * 16 + g + 1]       = a10;
            Cm_g[(row0 + 1) * 16 + g]     = a01; Cm_g[(row0 + 1) * 16 + g + 1] = a11;
        }
    }
    // ---- Phase D2: dt projection (rows 0..3), one (token,r) per thread ----
    if (tid < 128) {
        int tok = tid >> 2;
        const float4* xr = (const float4*)(smem + tok * K1_XCL_STR);
        const float4* wr = (const float4*)(xp_w + (tid & 3) * 128);
        float acc = 0.f;
        #pragma unroll
        for (int q = 0; q < 32; ++q) {
            float4 a = xr[q], w4 = wr[q];
            acc += dot4_(a, w4);
        }
        dtp_g[(size_t)(b * HW_ + l0) * 4 + tid] = acc;   // coalesced
        sdt[tid] = acc;
    }
    __syncthreads();

    // ---- Phase E (fused scan pass 1): this tile IS one chunk of 32 ----
    {
        const int e = tid >> 1;
        const int n0 = (tid & 1) * 8;
        float A[8];
        #pragma unroll
        for (int j = 0; j < 8; ++j) A[j] = -__expf(A_log[e * 16 + n0 + j]);
        float4 wdt = *(const float4*)(dt_w + e * 4);
        float dtb = dt_b[e];
        float h[8], cA[8];
        #pragma unroll
        for (int j = 0; j < 8; ++j) { h[j] = 0.f; cA[j] = 1.f; }
        for (int t = 0; t < 32; ++t) {
            float4 dv = *(const float4*)(sdt + t * 4);
            float d = softplusf_(wdt.x*dv.x + wdt.y*dv.y + wdt.z*dv.z + wdt.w*dv.w + dtb);
            float u = smem[t * K1_XCL_STR + e];
            float4 b0 = *(const float4*)(sB + t * 16 + n0);
            float4 b1 = *(const float4*)(sB + t * 16 + n0 + 4);
            float Bv[8]; *(float4*)(Bv) = b0; *(float4*)(Bv + 4) = b1;
            float du = d * u;
            #pragma unroll
            for (int j = 0; j < 8; ++j) {
                float dA = __expf(d * A[j]);
                h[j] = h[j] * dA + du * Bv[j];
                cA[j] *= dA;
            }
        }
        size_t so = (size_t)blockIdx.x * 2048 + tid * 8;
        *(float4*)(cumA_g + so)     = *(float4*)(cA);
        *(float4*)(cumA_g + so + 4) = *(float4*)(cA + 4);
        *(float4*)(hsum_g + so)     = *(float4*)(h);
        *(float4*)(hsum_g + so + 4) = *(float4*)(h + 4);
    }
}

// ---------------------------------------------------------------------------
// K3: cross-chunk exclusive combine (4096 independent streams, 512 steps).
// NOTE: Hin_g aliases cumA_g (loads of a batch precede its stores; each
// stream owns its column exclusively) — no __restrict__ here.
// ---------------------------------------------------------------------------
__global__ __launch_bounds__(256) void k3_combine(
    const float* cumA_g, const float* hsum_g, float* Hin_g)
{
    int gid = blockIdx.x * 256 + threadIdx.x;     // 0..4095
    int b = gid >> 11;
    int en = gid & 2047;
    float st = 0.f;
    size_t o = (size_t)b * SCH * 2048 + en;
    for (int cb = 0; cb < SCH; cb += 16) {
        float a[16], hs[16];
        #pragma unroll
        for (int k = 0; k < 16; ++k) {
            a[k]  = cumA_g[o + (size_t)k * 2048];
            hs[k] = hsum_g[o + (size_t)k * 2048];
        }
        #pragma unroll
        for (int k = 0; k < 16; ++k) {
            Hin_g[o + (size_t)k * 2048] = st;
            st = st * a[k] + hs[k];
        }
        o += (size_t)16 * 2048;
    }
}

// ---------------------------------------------------------------------------
// K4: spatial scan pass 2 + gating + out_proj + NCHW store + GN partials.
// grid 1024, block 256. out_proj: 2 c-rows x 4 tokens per thread.
// ---------------------------------------------------------------------------
__global__ __launch_bounds__(256) void k4_scan2(
    const float* __restrict__ xc_g, const float* __restrict__ sz_g,
    const float* __restrict__ Bm_g, const float* __restrict__ Cm_g,
    const float* __restrict__ dtp_g, const float* __restrict__ dt_w,
    const float* __restrict__ dt_b, const float* __restrict__ A_log,
    const float* __restrict__ Dp, const float* __restrict__ Hin_g,
    const float* __restrict__ out_w,
    float* __restrict__ spa_raw, float* __restrict__ part_spa)
{
    __shared__ __align__(16) float lds[9344];
    float* su  = lds;               // 4096: xc chunk [t][e]
    float* sB  = lds + 4096;        // 512
    float* sC  = lds + 4608;        // 512
    float* sdt = lds + 5120;        // 128
    float* yt  = lds + 5248;        // 4096: y'(t,e)
    float* ot  = lds;               // 2112: out(c,t) — overlays su post-scan
    __shared__ float wred[32];
    const int tid = threadIdx.x;
    const int b = blockIdx.x >> 9;
    const int ch = blockIdx.x & 511;
    const size_t rowbase = (size_t)b * HW_ + ch * SLC;

    const float4* u4 = (const float4*)(xc_g + rowbase * 128);
    #pragma unroll
    for (int j = 0; j < 4; ++j) ((float4*)su)[tid + j * 256] = u4[tid + j * 256];
    if (tid < 128) ((float4*)sB)[tid] = ((const float4*)(Bm_g + rowbase * 16))[tid];
    else           ((float4*)sC)[tid - 128] = ((const float4*)(Cm_g + rowbase * 16))[tid - 128];
    if (tid < 32)  ((float4*)sdt)[tid] = ((const float4*)(dtp_g + rowbase * 4))[tid];

    const int e = tid >> 1;
    const int nh = tid & 1;
    const int n0 = nh * 8;
    float A[8];
    #pragma unroll
    for (int j = 0; j < 8; ++j) A[j] = -__expf(A_log[e * 16 + n0 + j]);
    float4 wdt = *(const float4*)(dt_w + e * 4);
    float dtb = dt_b[e];
    float Dv = Dp[e];
    float h[8];
    size_t so = (size_t)blockIdx.x * 2048 + tid * 8;
    *(float4*)(h)     = *(const float4*)(Hin_g + so);
    *(float4*)(h + 4) = *(const float4*)(Hin_g + so + 4);
    __syncthreads();

    for (int t = 0; t < SLC; ++t) {
        float4 dv = *(const float4*)(sdt + t * 4);
        float d = softplusf_(wdt.x*dv.x + wdt.y*dv.y + wdt.z*dv.z + wdt.w*dv.w + dtb);
        float u = su[t * 128 + e];
        float4 b0 = *(const float4*)(sB + t * 16 + n0);
        float4 b1 = *(const float4*)(sB + t * 16 + n0 + 4);
        float4 c0 = *(const float4*)(sC + t * 16 + n0);
        float4 c1 = *(const float4*)(sC + t * 16 + n0 + 4);
        float Bv[8]; *(float4*)(Bv) = b0; *(float4*)(Bv + 4) = b1;
        float Cv[8]; *(float4*)(Cv) = c0; *(float4*)(Cv + 4) = c1;
        float du = d * u;
        float y = 0.f;
        #pragma unroll
        for (int j = 0; j < 8; ++j) {
            float dA = __expf(d * A[j]);
            h[j] = h[j] * dA + du * Bv[j];
            y += h[j] * Cv[j];
        }
        y += __shfl_xor(y, 1, 64);          // combine both n-halves
        if (nh == 0) yt[t * 128 + e] = y + u * Dv;
    }
    __syncthreads();

    // ---- gate pass: yt *= silu(z), coalesced float4 global reads ----
    {
        const float4* sz4 = (const float4*)(sz_g + rowbase * 128);
        #pragma unroll
        for (int j = 0; j < 4; ++j) {
            int f = tid + j * 256;
            float4 yv = ((float4*)yt)[f];
            float4 sv = sz4[f];
            yv.x *= sv.x; yv.y *= sv.y; yv.z *= sv.z; yv.w *= sv.w;
            ((float4*)yt)[f] = yv;
        }
    }
    __syncthreads();

    // ---- out_proj: 2 c-rows x 4 tokens per thread ----
    {
        const int c0 = (tid & 31) << 1;
        const int t0 = (tid >> 5) << 2;
        const float4* w0r = (const float4*)(out_w + c0 * 128);
        const float4* w1r = (const float4*)(out_w + (c0 + 1) * 128);
        float a0[4] = {0.f, 0.f, 0.f, 0.f}, a1[4] = {0.f, 0.f, 0.f, 0.f};
        #pragma unroll
        for (int q = 0; q < 32; ++q) {
            float4 w0 = w0r[q], w1 = w1r[q];
            #pragma unroll
            for (int j = 0; j < 4; ++j) {
                float4 yv = *(const float4*)(yt + (t0 + j) * 128 + q * 4);
                a0[j] += dot4_(w0, yv);
                a1[j] += dot4_(w1, yv);
            }
        }
        __syncthreads();   // all yt reads done before ot (overlaying su) writes
        #pragma unroll
        for (int j = 0; j < 4; ++j) {
            ot[c0 * 33 + t0 + j]       = a0[j];
            ot[(c0 + 1) * 33 + t0 + j] = a1[j];
        }
    }
    __syncthreads();

    // ---- NCHW store ----
    for (int i = tid; i < 64 * SLC; i += 256) {
        int c = i >> 5, t = i & 31;
        spa_raw[((size_t)b * NC + c) * HW_ + ch * SLC + t] = ot[c * 33 + t];
    }
    // ---- GroupNorm partial sums (4 groups of 16 channels) ----
    float s[4], s2[4];
    #pragma unroll
    for (int g = 0; g < 4; ++g) {
        float a = 0.f, a2 = 0.f;
        for (int i = tid; i < 512; i += 256) {
            int c = 16 * g + (i >> 5), t = i & 31;
            float v = ot[c * 33 + t];
            a += v; a2 += v * v;
        }
        s[g] = a; s2[g] = a2;
    }
    #pragma unroll
    for (int g = 0; g < 4; ++g) {
        #pragma unroll
        for (int o = 1; o < 64; o <<= 1) {
            s[g]  += __shfl_xor(s[g], o, 64);
            s2[g] += __shfl_xor(s2[g], o, 64);
        }
    }
    if ((tid & 63) == 0) {
        int w = tid >> 6;
        #pragma unroll
        for (int g = 0; g < 4; ++g) { wred[w*8 + g*2] = s[g]; wred[w*8 + g*2 + 1] = s2[g]; }
    }
    __syncthreads();
    if (tid < 8)   // transposed layout: [slot][block] for coalesced k5b reads
        part_spa[tid * 1024 + blockIdx.x] = wred[tid] + wred[8+tid] + wred[16+tid] + wred[24+tid];
}

// ---------------------------------------------------------------------------
// K5: spectral mamba fused; float4 LDS broadcasts; x staged from xT
// (one coalesced float4 per thread). grid 2048, block 256. LDS 31.9 KB.
// No launch-bounds VGPR clamp this round (A/B vs (256,2)'s pinned 128).
// ---------------------------------------------------------------------------
#define K5_STR 144

__global__ __launch_bounds__(256) void k5_spectral(
    const float* __restrict__ xT, const float* __restrict__ in_w,
    const float* __restrict__ conv_w, const float* __restrict__ conv_b,
    const float* __restrict__ xp_w, const float* __restrict__ dt_w,
    const float* __restrict__ dt_b, const float* __restrict__ A_log,
    const float* __restrict__ Dp, const float* __restrict__ out_w,
    float* __restrict__ spe_raw, float* __restrict__ part_spe)
{
    __shared__ __align__(16) float lds[7936];
    float* xcs  = lds;            // [s][t*16+e] stride 144 (2304); ys overlays
    float* sBn  = lds + 2304;     // B rows tile (2304); xin overlays first 1088
    float* sCn  = lds + 4608;     // C rows tile (2304); outs overlays first 1088
    float* souw = lds + 6912;     // out_w staged (1024)
    float* xin  = sBn;            // [j][c] stride 68 (16*68=1088)
    float* ys   = xcs;            // y' tile, same layout as xcs
    float* outs = sCn;            // [c][s] stride 17 (64*17=1088)
    __shared__ float wred[32];
    const int tid = threadIdx.x;
    const int b = blockIdx.x >> 10;
    const int hw0 = (blockIdx.x & 1023) << 4;
    const int s = tid >> 4;       // sequence in block (0..15)
    const int l = tid & 15;       // inner-channel e / state-row n (0..15)

    // ---- Phase 0: stage x tile (coalesced from xT) and out_w ----
    {
        const float4* xt4 = (const float4*)(xT + ((size_t)b * HW_ + hw0) * 64);
        int j = tid >> 4, c4 = (tid & 15) << 2;
        *(float4*)(xin + j * 68 + c4) = xt4[tid];
        ((float4*)souw)[tid] = ((const float4*)out_w)[tid];
    }
    // per-lane weights (global, L2-cached)
    float wi0[8], wi1[8];
    #pragma unroll
    for (int c = 0; c < 8; ++c) { wi0[c] = in_w[l*8 + c]; wi1[c] = in_w[(l+16)*8 + c]; }
    float cw0 = conv_w[l*4], cw1 = conv_w[l*4+1], cw2 = conv_w[l*4+2], cw3 = conv_w[l*4+3];
    float cb = conv_b[l];
    float dtw = dt_w[l], dtb = dt_b[l];
    float wdt[16], wB[16], wC[16];
    #pragma unroll
    for (int e = 0; e < 16; ++e) {
        wdt[e] = xp_w[e];
        wB[e]  = xp_w[(1 + l) * 16 + e];
        wC[e]  = xp_w[(17 + l) * 16 + e];
    }
    __syncthreads();

    // ---- Phase 1: in_proj (float4 broadcast reads) + conv, in registers ----
    float pre[8], sz[8];
    #pragma unroll
    for (int t = 0; t < 8; ++t) {
        float4 x0 = *(const float4*)(xin + s * 68 + t * 8);
        float4 x1 = *(const float4*)(xin + s * 68 + t * 8 + 4);
        float a0 = wi0[0]*x0.x + wi0[1]*x0.y + wi0[2]*x0.z + wi0[3]*x0.w
                 + wi0[4]*x1.x + wi0[5]*x1.y + wi0[6]*x1.z + wi0[7]*x1.w;
        float a1 = wi1[0]*x0.x + wi1[1]*x0.y + wi1[2]*x0.z + wi1[3]*x0.w
                 + wi1[4]*x1.x + wi1[5]*x1.y + wi1[6]*x1.z + wi1[7]*x1.w;
        pre[t] = a0; sz[t] = siluf_(a1);
    }
    float xcv[8];
    #pragma unroll
    for (int t = 0; t < 8; ++t) {
        float v = cb + cw3 * pre[t];
        if (t >= 1) v += cw2 * pre[t-1];
        if (t >= 2) v += cw1 * pre[t-2];
        if (t >= 3) v += cw0 * pre[t-3];
        xcv[t] = siluf_(v);
    }
    #pragma unroll
    for (int t = 0; t < 8; ++t) xcs[s * K5_STR + t * 16 + l] = xcv[t];
    __syncthreads();

    // ---- Phase 2: x-projections; lane l computes rows B_l, C_l, dt ----
    float del[8];
    #pragma unroll
    for (int t = 0; t < 8; ++t) {
        const float4* xr = (const float4*)(xcs + s * K5_STR + t * 16);
        float4 v0 = xr[0], v1 = xr[1], v2 = xr[2], v3 = xr[3];
        float bn = wB[0]*v0.x + wB[1]*v0.y + wB[2]*v0.z + wB[3]*v0.w
                 + wB[4]*v1.x + wB[5]*v1.y + wB[6]*v1.z + wB[7]*v1.w
                 + wB[8]*v2.x + wB[9]*v2.y + wB[10]*v2.z + wB[11]*v2.w
                 + wB[12]*v3.x + wB[13]*v3.y + wB[14]*v3.z + wB[15]*v3.w;
        float cn = wC[0]*v0.x + wC[1]*v0.y + wC[2]*v0.z + wC[3]*v0.w
                 + wC[4]*v1.x + wC[5]*v1.y + wC[6]*v1.z + wC[7]*v1.w
                 + wC[8]*v2.x + wC[9]*v2.y + wC[10]*v2.z + wC[11]*v2.w
                 + wC[12]*v3.x + wC[13]*v3.y + wC[14]*v3.z + wC[15]*v3.w;
        float d0 = wdt[0]*v0.x + wdt[1]*v0.y + wdt[2]*v0.z + wdt[3]*v0.w
                 + wdt[4]*v1.x + wdt[5]*v1.y + wdt[6]*v1.z + wdt[7]*v1.w
                 + wdt[8]*v2.x + wdt[9]*v2.y + wdt[10]*v2.z + wdt[11]*v2.w
                 + wdt[12]*v3.x + wdt[13]*v3.y + wdt[14]*v3.z + wdt[15]*v3.w;
        sBn[s * K5_STR + t * 16 + l] = bn;
        sCn[s * K5_STR + t * 16 + l] = cn;
        del[t] = softplusf_(d0 * dtw + dtb);
    }
    __syncthreads();

    // ---- Phase 3: selective scan, 16 states/lane, B/C via b128 broadcast ----
    float A[16];
    #pragma unroll
    for (int n = 0; n < 16; ++n) A[n] = -__expf(A_log[l * 16 + n]);
    float Dv = Dp[l];
    float h[16];
    #pragma unroll
    for (int n = 0; n < 16; ++n) h[n] = 0.f;
    #pragma unroll
    for (int t = 0; t < 8; ++t) {
        float d = del[t], u = xcv[t];
        float du = d * u;
        float y = 0.f;
        const float4* Bp = (const float4*)(sBn + s * K5_STR + t * 16);
        const float4* Cp = (const float4*)(sCn + s * K5_STR + t * 16);
        #pragma unroll
        for (int q = 0; q < 4; ++q) {
            float4 Bq = Bp[q], Cq = Cp[q];
            float dA;
            dA = __expf(d*A[4*q+0]); h[4*q+0] = h[4*q+0]*dA + du*Bq.x; y += h[4*q+0]*Cq.x;
            dA = __expf(d*A[4*q+1]); h[4*q+1] = h[4*q+1]*dA + du*Bq.y; y += h[4*q+1]*Cq.y;
            dA = __expf(d*A[4*q+2]); h[4*q+2] = h[4*q+2]*dA + du*Bq.z; y += h[4*q+2]*Cq.z;
            dA = __expf(d*A[4*q+3]); h[4*q+3] = h[4*q+3]*dA + du*Bq.w; y += h[4*q+3]*Cq.w;
        }
        ys[s * K5_STR + t * 16 + l] = (y + u * Dv) * sz[t];
    }
    __syncthreads();

    // ---- Phase 4: out_proj (weights + y via b128), 4 outputs per lane ----
    {
        int t = l >> 1;
        int db = (l & 1) * 4;
        const float4* yr = (const float4*)(ys + s * K5_STR + t * 16);
        float4 y0 = yr[0], y1 = yr[1], y2 = yr[2], y3 = yr[3];
        #pragma unroll
        for (int jj = 0; jj < 4; ++jj) {
            int dd = db + jj;
            const float4* wr = (const float4*)(souw + dd * 16);
            float4 w0 = wr[0], w1 = wr[1], w2 = wr[2], w3 = wr[3];
            float acc = dot4_(w0, y0) + dot4_(w1, y1) + dot4_(w2, y2) + dot4_(w3, y3);
            outs[(t * 8 + dd) * 17 + s] = acc;   // channel c = t*8+dd
        }
    }
    __syncthreads();

    // ---- Phase 5: coalesced NCHW store + GN partials (k == group g) ----
    float sg[4], sg2[4];
    #pragma unroll
    for (int k = 0; k < 4; ++k) {
        int i = tid + k * 256;
        int c = i >> 4, j = i & 15;
        float v = outs[c * 17 + j];
        spe_raw[((size_t)b * NC + c) * HW_ + hw0 + j] = v;
        sg[k] = v; sg2[k] = v * v;
    }
    #pragma unroll
    for (int k = 0; k < 4; ++k) {
        #pragma unroll
        for (int o = 1; o < 64; o <<= 1) {
            sg[k]  += __shfl_xor(sg[k], o, 64);
            sg2[k] += __shfl_xor(sg2[k], o, 64);
        }
    }
    if ((tid & 63) == 0) {
        int w = tid >> 6;
        #pragma unroll
        for (int k = 0; k < 4; ++k) { wred[w*8 + k*2] = sg[k]; wred[w*8 + k*2 + 1] = sg2[k]; }
    }
    __syncthreads();
    if (tid < 8)   // transposed layout: [slot][block]
        part_spe[tid * 2048 + blockIdx.x] = wred[tid] + wred[8+tid] + wred[16+tid] + wred[24+tid];
}

// ---------------------------------------------------------------------------
// K5b: reduce GN partials -> (mean, rstd); coalesced float4 reads.
// partials layout: [slot=g*2+st][block], spa 8x1024, spe 8x2048.
// ---------------------------------------------------------------------------
__global__ __launch_bounds__(256) void k5b_stats(
    const float* __restrict__ part_spa, const float* __restrict__ part_spe,
    float* __restrict__ stats)
{
    __shared__ float fina[16], fine_[16];
    const int tid = threadIdx.x;
    const int combo = tid >> 4;      // bb*8 + g*2 + st
    const int ln = tid & 15;
    const int slot = combo & 7, bb = combo >> 3;
    {
        const float4* p = (const float4*)(part_spa + slot * 1024 + bb * 512);
        float a = 0.f;
        #pragma unroll
        for (int k = 0; k < 8; ++k) {
            float4 v = p[ln * 8 + k];
            a += v.x + v.y + v.z + v.w;
        }
        #pragma unroll
        for (int o = 1; o < 16; o <<= 1) a += __shfl_xor(a, o, 64);
        if (ln == 0) fina[combo] = a;
    }
    {
        const float4* p = (const float4*)(part_spe + slot * 2048 + bb * 1024);
        float a = 0.f;
        #pragma unroll
        for (int k = 0; k < 16; ++k) {
            float4 v = p[ln * 16 + k];
            a += v.x + v.y + v.z + v.w;
        }
        #pragma unroll
        for (int o = 1; o < 16; o <<= 1) a += __shfl_xor(a, o, 64);
        if (ln == 0) fine_[combo] = a;
    }
    __syncthreads();
    if (tid < 16) {
        int branch = tid >> 3, bb2 = (tid >> 2) & 1, g = tid & 3;
        const float* fin = branch ? fine_ : fina;
        float S  = fin[bb2 * 8 + g * 2];
        float S2 = fin[bb2 * 8 + g * 2 + 1];
        const float N = 262144.f;     // 16 channels * 16384 positions
        float mu = S / N;
        float var = S2 / N - mu * mu;
        stats[tid * 2] = mu;
        stats[tid * 2 + 1] = rsqrtf(var + 1e-5f);
    }
}

// ---------------------------------------------------------------------------
// K6: GN-normalize + silu + residual for both branches, softmax fuse, store
// ---------------------------------------------------------------------------
__global__ __launch_bounds__(256) void k6_fuse(
    const float* __restrict__ x, const float* __restrict__ spa_raw,
    const float* __restrict__ spe_raw, const float* __restrict__ stats,
    const float* __restrict__ gwa, const float* __restrict__ gba,
    const float* __restrict__ gwe, const float* __restrict__ gbe,
    const float* __restrict__ fw, float* __restrict__ out)
{
    size_t i4 = (size_t)blockIdx.x * 256 + threadIdx.x;
    size_t base = i4 * 4;
    int b = (int)(base >> 20);
    int rem = (int)(base & 1048575);
    int c = rem >> 14;
    int g = c >> 4;
    int sidx = (b * 4 + g) * 2;
    float ma = stats[sidx],      ra = stats[sidx + 1];
    float me = stats[16 + sidx], re = stats[16 + sidx + 1];
    float wa = gwa[c], ba = gba[c], we = gwe[c], be = gbe[c];
    float f0 = fw[0], f1 = fw[1];
    float mx = fmaxf(f0, f1);
    float e0 = __expf(f0 - mx), e1 = __expf(f1 - mx);
    float inv = 1.f / (e0 + e1);
    float w0 = e0 * inv, w1 = e1 * inv;
    float4 xv = *(const float4*)(x + base);
    float4 av = *(const float4*)(spa_raw + base);
    float4 ev = *(const float4*)(spe_raw + base);
    float xr[4] = {xv.x, xv.y, xv.z, xv.w};
    float ar[4] = {av.x, av.y, av.z, av.w};
    float er[4] = {ev.x, ev.y, ev.z, ev.w};
    float orr[4];
    #pragma unroll
    for (int k = 0; k < 4; ++k) {
        float spa = siluf_((ar[k] - ma) * ra * wa + ba) + xr[k];
        float spe = siluf_((er[k] - me) * re * we + be) + xr[k];
        orr[k] = spa * w0 + spe * w1 + xr[k];
    }
    float4 ov = {orr[0], orr[1], orr[2], orr[3]};
    *(float4*)(out + base) = ov;
}

// ---------------------------------------------------------------------------
extern "C" void kernel_launch(void* const* d_in, const int* in_sizes, int n_in,
                              void* d_out, int out_size, void* d_ws, size_t ws_size,
                              hipStream_t stream)
{
    const float* x      = (const float*)d_in[0];
    const float* a_inw  = (const float*)d_in[1];
    const float* a_cw   = (const float*)d_in[2];
    const float* a_cb   = (const float*)d_in[3];
    const float* a_xp   = (const float*)d_in[4];
    const float* a_dtw  = (const float*)d_in[5];
    const float* a_dtb  = (const float*)d_in[6];
    const float* a_Alog = (const float*)d_in[7];
    const float* a_D    = (const float*)d_in[8];
    const float* a_ow   = (const float*)d_in[9];
    const float* e_inw  = (const float*)d_in[10];
    const float* e_cw   = (const float*)d_in[11];
    const float* e_cb   = (const float*)d_in[12];
    const float* e_xp   = (const float*)d_in[13];
    const float* e_dtw  = (const float*)d_in[14];
    const float* e_dtb  = (const float*)d_in[15];
    const float* e_Alog = (const float*)d_in[16];
    const float* e_D    = (const float*)d_in[17];
    const float* e_ow   = (const float*)d_in[18];
    const float* gwa    = (const float*)d_in[19];
    const float* gba    = (const float*)d_in[20];
    const float* gwe    = (const float*)d_in[21];
    const float* gbe    = (const float*)d_in[22];
    const float* fw     = (const float*)d_in[23];

    float* ws    = (float*)d_ws;
    float* xc    = ws;                    // 4194304
    float* sz    = xc    + 4194304;       // 4194304
    float* Bm    = sz    + 4194304;       // 524288
    float* Cm    = Bm    + 524288;        // 524288
    float* dtp   = Cm    + 524288;        // 131072
    float* cumA  = dtp   + 131072;        // 2097152 (also serves as Hin)
    float* hsum  = cumA  + 2097152;       // 2097152
    float* xT    = hsum  + 2097152;       // 2097152
    float* spa_r = xT    + 2097152;       // 2097152
    float* spe_r = spa_r + 2097152;       // 2097152
    float* pspa  = spe_r + 2097152;       // 8*1024
    float* pspe  = pspa  + 8192;          // 8*2048
    float* stats = pspe  + 16384;         // 32

    k0_transpose<<<512, 256, 0, stream>>>(x, xT);
    k1_spatial_pre<<<1024, 256, 0, stream>>>(xT, a_inw, a_cw, a_cb, a_xp, a_dtw,
                                             a_dtb, a_Alog,
                                             xc, sz, dtp, Bm, Cm, cumA, hsum);
    k3_combine<<<16, 256, 0, stream>>>(cumA, hsum, cumA);   // Hin aliases cumA
    k5_spectral<<<2048, 256, 0, stream>>>(xT, e_inw, e_cw, e_cb, e_xp, e_dtw, e_dtb,
                                          e_Alog, e_D, e_ow, spe_r, pspe);
    k4_scan2<<<1024, 256, 0, stream>>>(xc, sz, Bm, Cm, dtp, a_dtw, a_dtb, a_Alog,
                                       a_D, cumA, a_ow, spa_r, pspa);
    k5b_stats<<<1, 256, 0, stream>>>(pspa, pspe, stats);
    k6_fuse<<<2048, 256, 0, stream>>>(x, spa_r, spe_r, stats, gwa, gba, gwe, gbe, fw,
                                      (float*)d_out);
}